// Round 4
// baseline (6572.580 us; speedup 1.0000x reference)
//
#include <hip/hip_runtime.h>

#define N_ROWS 16384
#define N_EMB  8192
#define DIM    512
#define NCAND  16

// ---------------------------------------------------------------------------
// ws layout:
//   [0]    double lossAcc (16 B, zeroed)
//   [16]   int cand[N_ROWS * NCAND]   (1 MB)
// ---------------------------------------------------------------------------

#define SWAPF(a, b) { float _tf = a; a = b; b = _tf; }
#define SWAPI(a, b) { int   _ti = a; a = b; b = _ti; }

// Phase 1: fused fp32 GEMM (C = z_e . cb^T) + per-row top-16 candidates by
// approximate score (-C). Superset containment margin ~2e-3 >> all rounding.
__launch_bounds__(256, 2)
__global__ void topk_gemm_kernel(const float* __restrict__ ze,
                                 const float* __restrict__ cb,
                                 int* __restrict__ cand) {
    __shared__ union {
        struct { float As[32][36]; float Bs[32][132]; } mm;   // 21.5 KB
        struct { float cd[32][256]; int ci[32][256]; } ca;    // 64 KB
    } sh;

    const int t  = threadIdx.x;
    const int tx = t & 31;
    const int ty = t >> 5;
    const int rowBase = blockIdx.x * 32;

    float d8v[4][8];
    int   i8v[4][8];
    #pragma unroll
    for (int r = 0; r < 4; ++r)
        #pragma unroll
        for (int s = 0; s < 8; ++s) { d8v[r][s] = 3.0e38f; i8v[r][s] = 0; }

    const int sRow = t >> 3;
    const int sK4  = t & 7;

    for (int ct = 0; ct < N_EMB / 128; ++ct) {
        const int cbase = ct * 128;
        float acc[4][4];
        #pragma unroll
        for (int r = 0; r < 4; ++r)
            #pragma unroll
            for (int c = 0; c < 4; ++c) acc[r][c] = 0.0f;

        for (int k0 = 0; k0 < DIM; k0 += 32) {
            __syncthreads();
            {
                float4 av = *(const float4*)&ze[(size_t)(rowBase + sRow) * DIM + k0 + sK4 * 4];
                *(float4*)&sh.mm.As[sRow][sK4 * 4] = av;
            }
            #pragma unroll
            for (int jj = 0; jj < 4; ++jj) {
                int i   = t + jj * 256;
                int col = i >> 3;
                int k4  = i & 7;
                float4 bv = *(const float4*)&cb[(size_t)(cbase + col) * DIM + k0 + k4 * 4];
                sh.mm.Bs[k4 * 4 + 0][col] = bv.x;
                sh.mm.Bs[k4 * 4 + 1][col] = bv.y;
                sh.mm.Bs[k4 * 4 + 2][col] = bv.z;
                sh.mm.Bs[k4 * 4 + 3][col] = bv.w;
            }
            __syncthreads();

            #pragma unroll
            for (int k = 0; k < 32; k += 4) {
                float a[4][4];
                float b[4][4];
                #pragma unroll
                for (int r = 0; r < 4; ++r) {
                    float4 av = *(const float4*)&sh.mm.As[ty * 4 + r][k];
                    a[r][0] = av.x; a[r][1] = av.y; a[r][2] = av.z; a[r][3] = av.w;
                }
                #pragma unroll
                for (int kk = 0; kk < 4; ++kk) {
                    float4 bv = *(const float4*)&sh.mm.Bs[k + kk][tx * 4];
                    b[kk][0] = bv.x; b[kk][1] = bv.y; b[kk][2] = bv.z; b[kk][3] = bv.w;
                }
                #pragma unroll
                for (int kk = 0; kk < 4; ++kk)
                    #pragma unroll
                    for (int r = 0; r < 4; ++r)
                        #pragma unroll
                        for (int c = 0; c < 4; ++c)
                            acc[r][c] = fmaf(a[r][kk], b[kk][c], acc[r][c]);
            }
        }

        #pragma unroll
        for (int r = 0; r < 4; ++r) {
            #pragma unroll
            for (int c = 0; c < 4; ++c) {
                float dv = -acc[r][c];
                int   j  = cbase + tx * 4 + c;
                if (dv < d8v[r][7]) {
                    d8v[r][7] = dv; i8v[r][7] = j;
                    #pragma unroll
                    for (int s = 7; s > 0; --s)
                        if (d8v[r][s] < d8v[r][s - 1]) { SWAPF(d8v[r][s], d8v[r][s - 1]); SWAPI(i8v[r][s], i8v[r][s - 1]); }
                }
            }
        }
    }

    __syncthreads();
    #pragma unroll
    for (int r = 0; r < 4; ++r)
        #pragma unroll
        for (int s = 0; s < 8; ++s) {
            sh.ca.cd[ty * 4 + r][tx * 8 + s] = d8v[r][s];
            sh.ca.ci[ty * 4 + r][tx * 8 + s] = i8v[r][s];
        }
    __syncthreads();

    if (t < 32) {
        float d16[NCAND]; int i16[NCAND];
        #pragma unroll
        for (int s = 0; s < NCAND; ++s) { d16[s] = 3.0e38f; i16[s] = 0; }
        for (int e = 0; e < 256; ++e) {
            float dv = sh.ca.cd[t][e];
            int   j  = sh.ca.ci[t][e];
            if (dv < d16[NCAND - 1]) {
                d16[NCAND - 1] = dv; i16[NCAND - 1] = j;
                #pragma unroll
                for (int s = NCAND - 1; s > 0; --s)
                    if (d16[s] < d16[s - 1]) { SWAPF(d16[s], d16[s - 1]); SWAPI(i16[s], i16[s - 1]); }
            }
        }
        #pragma unroll
        for (int s = 0; s < NCAND; ++s)
            cand[(size_t)(rowBase + t) * NCAND + s] = i16[s];
    }
}

// Phase 2: bit-replicate the numpy fp32 pipeline on the 16 candidates.
//  znorm: numpy pairwise f32 (512 -> (B0+B1)+(B2+B3); 128-block base case =
//         8 strided accumulators, combined ((r0+r1)+(r2+r3))+((r4+r5)+(r6+r7)))
//  C:     OpenBLAS sgemm accumulation: KC=384 split — fl(chain k<384) +
//         fl(chain 384..511), each a sequential single-accumulator FMA chain
//  q    = fl(znorm - 2*C)    (2*C exact; +wnorm < half-ulp, provably no-op)
//  top-4 by (q, index) — stable-sort tie-break, matching np/lax top_k.
// One wave per row; lane c (<16) runs candidate c's chain; z broadcast in LDS.
__global__ void rescore_kernel(const float* __restrict__ ze,
                               const float* __restrict__ cb,
                               const int* __restrict__ cand,
                               float* __restrict__ out_zq,
                               float* __restrict__ out_khot,
                               double* __restrict__ lossAcc) {
    __shared__ float zsh[4][DIM];
    const int wv = threadIdx.x >> 6;
    const int lane = threadIdx.x & 63;
    const int row = blockIdx.x * 4 + wv;

    {
        const float* zp = ze + (size_t)row * DIM + lane * 8;
        float4 v0 = *(const float4*)zp;
        float4 v1 = *(const float4*)(zp + 4);
        *(float4*)&zsh[wv][lane * 8]     = v0;
        *(float4*)&zsh[wv][lane * 8 + 4] = v1;
    }
    __syncthreads();

    // znorm, numpy-pairwise (verified replication from R1)
    float racc = 0.0f;
    {
        const int b = (lane >> 3) & 3;
        const int j = lane & 7;
        const float* zr = &zsh[wv][128 * b + j];
        #pragma unroll
        for (int i = 0; i < 16; ++i) {
            float zk = zr[8 * i];
            float sq = zk * zk;
            asm volatile("" : "+v"(sq));   // block FMA contraction into the add
            racc = racc + sq;
        }
    }
    float t1 = racc + __shfl_xor(racc, 1, 64);
    float t2 = t1 + __shfl_xor(t1, 2, 64);
    float t3 = t2 + __shfl_xor(t2, 4, 64);
    float zn = (__shfl(t3, 0, 64) + __shfl(t3, 8, 64))
             + (__shfl(t3, 16, 64) + __shfl(t3, 24, 64));

    // candidate chains: KC=384 split, sequential FMA, single accumulator each
    float qv = 3.0e38f;
    int   idxv = 0x7fffffff;
    if (lane < NCAND) {
        idxv = cand[(size_t)row * NCAND + lane];
        const float* wp = cb + (size_t)idxv * DIM;
        const float* zz = zsh[wv];
        float acc1 = 0.0f;
        for (int k = 0; k < 384; k += 8) {
            float4 wa = *(const float4*)(wp + k);
            float4 wb = *(const float4*)(wp + k + 4);
            acc1 = __builtin_fmaf(zz[k + 0], wa.x, acc1);
            acc1 = __builtin_fmaf(zz[k + 1], wa.y, acc1);
            acc1 = __builtin_fmaf(zz[k + 2], wa.z, acc1);
            acc1 = __builtin_fmaf(zz[k + 3], wa.w, acc1);
            acc1 = __builtin_fmaf(zz[k + 4], wb.x, acc1);
            acc1 = __builtin_fmaf(zz[k + 5], wb.y, acc1);
            acc1 = __builtin_fmaf(zz[k + 6], wb.z, acc1);
            acc1 = __builtin_fmaf(zz[k + 7], wb.w, acc1);
        }
        float acc2 = 0.0f;
        for (int k = 384; k < 512; k += 8) {
            float4 wa = *(const float4*)(wp + k);
            float4 wb = *(const float4*)(wp + k + 4);
            acc2 = __builtin_fmaf(zz[k + 0], wa.x, acc2);
            acc2 = __builtin_fmaf(zz[k + 1], wa.y, acc2);
            acc2 = __builtin_fmaf(zz[k + 2], wa.z, acc2);
            acc2 = __builtin_fmaf(zz[k + 3], wa.w, acc2);
            acc2 = __builtin_fmaf(zz[k + 4], wb.x, acc2);
            acc2 = __builtin_fmaf(zz[k + 5], wb.y, acc2);
            acc2 = __builtin_fmaf(zz[k + 6], wb.z, acc2);
            acc2 = __builtin_fmaf(zz[k + 7], wb.w, acc2);
        }
        float Cv = acc1 + acc2;
        qv = zn - 2.0f * Cv;   // 2*C exact; single rounding, same as np
    }

    // gather all 16 (q, idx); select top-4 by (q, index)
    float q[NCAND]; int id[NCAND];
    #pragma unroll
    for (int c = 0; c < NCAND; ++c) {
        q[c]  = __shfl(qv, c, 64);
        id[c] = __shfl(idxv, c, 64);
    }
    int selIdx[4];
    bool used[NCAND];
    #pragma unroll
    for (int c = 0; c < NCAND; ++c) used[c] = false;
    #pragma unroll
    for (int s = 0; s < 4; ++s) {
        float bq = 3.0e38f; int bi = 0x7fffffff; int bc = -1;
        #pragma unroll
        for (int c = 0; c < NCAND; ++c) {
            bool better = !used[c] && (q[c] < bq || (q[c] == bq && id[c] < bi));
            if (better) { bq = q[c]; bi = id[c]; bc = c; }
        }
        selIdx[s] = bi;
        #pragma unroll
        for (int c = 0; c < NCAND; ++c) used[c] = used[c] || (c == bc);
    }

    // z_q = mean of 4 selected rows
    float zq[8] = { 0, 0, 0, 0, 0, 0, 0, 0 };
    #pragma unroll
    for (int s = 0; s < 4; ++s) {
        const float* wp = cb + (size_t)selIdx[s] * DIM + lane * 8;
        float4 w0 = *(const float4*)wp;
        float4 w1 = *(const float4*)(wp + 4);
        zq[0] += w0.x; zq[1] += w0.y; zq[2] += w0.z; zq[3] += w0.w;
        zq[4] += w1.x; zq[5] += w1.y; zq[6] += w1.z; zq[7] += w1.w;
    }

    float zf[8];
    {
        const float* zz = &zsh[wv][lane * 8];
        #pragma unroll
        for (int i = 0; i < 8; ++i) zf[i] = zz[i];
    }
    float o[8];
    double l = 0.0;
    #pragma unroll
    for (int i = 0; i < 8; ++i) {
        float zqf  = zq[i] * 0.25f;
        float diff = zqf - zf[i];
        o[i] = zf[i] + diff;
        double ld = (double)diff;
        l += ld * ld;
    }
    {
        float* op = out_zq + (size_t)row * DIM + lane * 8;
        float4 v0 = { o[0], o[1], o[2], o[3] };
        float4 v1 = { o[4], o[5], o[6], o[7] };
        *(float4*)op = v0;
        *(float4*)(op + 4) = v1;
    }
    #pragma unroll
    for (int m = 32; m; m >>= 1) l += __shfl_xor(l, m, 64);
    if (lane == 0) atomicAdd(lossAcc, l);

    if (lane < 4)
        out_khot[(size_t)row * N_EMB + selIdx[lane]] = 1.0f;
}

__global__ void finalize_kernel(const double* __restrict__ lossAcc,
                                float* __restrict__ out_loss) {
    if (threadIdx.x == 0 && blockIdx.x == 0)
        out_loss[0] = (float)(lossAcc[0] * (1.25 / ((double)N_ROWS * (double)DIM)));
}

extern "C" void kernel_launch(void* const* d_in, const int* in_sizes, int n_in,
                              void* d_out, int out_size, void* d_ws, size_t ws_size,
                              hipStream_t stream) {
    (void)in_sizes; (void)n_in; (void)out_size; (void)ws_size;
    const float* ze = (const float*)d_in[0];
    const float* cb = (const float*)d_in[1];

    float* out      = (float*)d_out;
    float* out_zq   = out;                                   // [16384, 512]
    float* out_loss = out + (size_t)N_ROWS * DIM;            // [1]
    float* out_khot = out_loss + 1;                          // [16384, 8192]

    double* lossAcc = (double*)d_ws;
    int*    cand    = (int*)((char*)d_ws + 16);

    hipMemsetAsync(lossAcc, 0, 16, stream);
    hipMemsetAsync(out_khot, 0, (size_t)N_ROWS * N_EMB * sizeof(float), stream);

    topk_gemm_kernel<<<N_ROWS / 32, 256, 0, stream>>>(ze, cb, cand);
    rescore_kernel<<<N_ROWS / 4, 256, 0, stream>>>(ze, cb, cand, out_zq, out_khot, lossAcc);
    finalize_kernel<<<1, 64, 0, stream>>>(lossAcc, out_loss);
}

// Round 5
// 1908.403 us; speedup vs baseline: 3.4440x; 3.4440x over previous
//
#include <hip/hip_runtime.h>

#define N_ROWS 16384
#define N_EMB  8192
#define DIM    512
#define NCAND  16

// ---------------------------------------------------------------------------
// ws layout:
//   [0]    double lossAcc (16 B, zeroed)
//   [16]   int cand[N_ROWS * NCAND]   (1 MB)
// scores (fp32, 512 MB) live in the out_khot region and are consumed by the
// scan kernel BEFORE out_khot is zeroed.
// ---------------------------------------------------------------------------

#define SWAPF(a, b) { float _tf = a; a = b; b = _tf; }
#define SWAPI(a, b) { int   _ti = a; a = b; b = _ti; }

typedef short  bhalf8  __attribute__((ext_vector_type(8)));
typedef float  floatx4 __attribute__((ext_vector_type(4)));

__device__ __forceinline__ unsigned short f2b(float f) {
    unsigned u = __builtin_bit_cast(unsigned, f);
    unsigned r = (u + 0x7fffu + ((u >> 16) & 1u)) >> 16;   // RNE
    return (unsigned short)r;
}
__device__ __forceinline__ unsigned pk2(float a, float b) {
    return (unsigned)f2b(a) | ((unsigned)f2b(b) << 16);
}

// Phase 1a: bf16 MFMA GEMM, scores[row][col] = -(z_e . cb^T)[row][col] (fp32).
// 128x128 tile, BK=32, 16x16x32 MFMA, 4 waves as 2x2 of 64x64.
// fp32->bf16 conversion fused into LDS staging. LDS rows padded to 40 ushorts
// (80 B stride): frag-read bank-quads (m*5+q)%8 and staging-write quads
// (m*5+c)%8 are uniform -> no extra conflicts.
__launch_bounds__(256, 2)
__global__ void score_gemm_kernel(const float* __restrict__ ze,
                                  const float* __restrict__ cb,
                                  float* __restrict__ scores) {
    __shared__ unsigned short As[128][40];   // 10 KB
    __shared__ unsigned short Bs[128][40];   // 10 KB

    const int t    = threadIdx.x;
    const int lane = t & 63;
    const int w    = t >> 6;
    const int rowBase = blockIdx.y * 128;
    const int colBase = blockIdx.x * 128;

    const int m  = lane & 15;     // C col within 16-tile / A row / B col
    const int q  = lane >> 4;     // quad
    const int wr = (w >> 1) * 64; // wave row offset
    const int wc = (w & 1) * 64;  // wave col offset

    floatx4 acc[4][4];
    #pragma unroll
    for (int i = 0; i < 4; ++i)
        #pragma unroll
        for (int j = 0; j < 4; ++j)
            acc[i][j] = (floatx4){0.0f, 0.0f, 0.0f, 0.0f};

    const int sr = t >> 1;          // staging row 0..127
    const int sk = (t & 1) * 16;    // staging k offset 0 or 16
    const float* pa = ze + (size_t)(rowBase + sr) * DIM + sk;
    const float* pb = cb + (size_t)(colBase + sr) * DIM + sk;

    for (int k0 = 0; k0 < DIM; k0 += 32) {
        __syncthreads();
        {
            float4 a0 = *(const float4*)(pa + k0);
            float4 a1 = *(const float4*)(pa + k0 + 4);
            float4 a2 = *(const float4*)(pa + k0 + 8);
            float4 a3 = *(const float4*)(pa + k0 + 12);
            uint4 ua0 = { pk2(a0.x, a0.y), pk2(a0.z, a0.w), pk2(a1.x, a1.y), pk2(a1.z, a1.w) };
            uint4 ua1 = { pk2(a2.x, a2.y), pk2(a2.z, a2.w), pk2(a3.x, a3.y), pk2(a3.z, a3.w) };
            *(uint4*)&As[sr][sk]     = ua0;
            *(uint4*)&As[sr][sk + 8] = ua1;

            float4 b0 = *(const float4*)(pb + k0);
            float4 b1 = *(const float4*)(pb + k0 + 4);
            float4 b2 = *(const float4*)(pb + k0 + 8);
            float4 b3 = *(const float4*)(pb + k0 + 12);
            uint4 ub0 = { pk2(b0.x, b0.y), pk2(b0.z, b0.w), pk2(b1.x, b1.y), pk2(b1.z, b1.w) };
            uint4 ub1 = { pk2(b2.x, b2.y), pk2(b2.z, b2.w), pk2(b3.x, b3.y), pk2(b3.z, b3.w) };
            *(uint4*)&Bs[sr][sk]     = ub0;
            *(uint4*)&Bs[sr][sk + 8] = ub1;
        }
        __syncthreads();

        bhalf8 af[4], bf[4];
        #pragma unroll
        for (int i = 0; i < 4; ++i) af[i] = *(bhalf8*)&As[wr + i * 16 + m][q * 8];
        #pragma unroll
        for (int j = 0; j < 4; ++j) bf[j] = *(bhalf8*)&Bs[wc + j * 16 + m][q * 8];
        #pragma unroll
        for (int i = 0; i < 4; ++i)
            #pragma unroll
            for (int j = 0; j < 4; ++j)
                acc[i][j] = __builtin_amdgcn_mfma_f32_16x16x32_bf16(af[i], bf[j], acc[i][j], 0, 0, 0);
    }

    // store scores = -C. C/D layout: col = lane&15, row = quad*4 + reg.
    #pragma unroll
    for (int i = 0; i < 4; ++i) {
        #pragma unroll
        for (int reg = 0; reg < 4; ++reg) {
            int row = rowBase + wr + i * 16 + q * 4 + reg;
            float* sp = scores + (size_t)row * N_EMB + colBase + wc + m;
            #pragma unroll
            for (int j = 0; j < 4; ++j)
                sp[j * 16] = -acc[i][j][reg];
        }
    }
}

// Phase 1b: wave-per-row scan of fp32 scores -> per-row top-16 candidate idxs.
// Per-lane top-8 (union provably contains global top-9+), lane-0 merge.
__global__ void topk_scan_kernel(const float* __restrict__ scores,
                                 int* __restrict__ cand) {
    __shared__ float sd[4][512];
    __shared__ int   si[4][512];
    const int t    = threadIdx.x;
    const int wv   = t >> 6;
    const int lane = t & 63;
    const int row  = blockIdx.x * 4 + wv;
    const float* sp = scores + (size_t)row * N_EMB;

    float d8[8]; int i8[8];
    #pragma unroll
    for (int s = 0; s < 8; ++s) { d8[s] = 3.0e38f; i8[s] = 0; }

    for (int it = 0; it < 32; ++it) {
        int col = it * 256 + lane * 4;
        float4 v = *(const float4*)(sp + col);
        float vv[4] = { v.x, v.y, v.z, v.w };
        #pragma unroll
        for (int c = 0; c < 4; ++c) {
            float dv = vv[c];
            if (dv < d8[7]) {
                d8[7] = dv; i8[7] = col + c;
                #pragma unroll
                for (int s = 7; s > 0; --s)
                    if (d8[s] < d8[s - 1]) { SWAPF(d8[s], d8[s - 1]); SWAPI(i8[s], i8[s - 1]); }
            }
        }
    }

    #pragma unroll
    for (int s = 0; s < 8; ++s) {
        sd[wv][lane * 8 + s] = d8[s];
        si[wv][lane * 8 + s] = i8[s];
    }
    __syncthreads();

    if (lane == 0) {
        float d16[NCAND]; int i16[NCAND];
        #pragma unroll
        for (int s = 0; s < NCAND; ++s) { d16[s] = 3.0e38f; i16[s] = 0; }
        for (int e = 0; e < 512; ++e) {
            float dv = sd[wv][e];
            if (dv < d16[NCAND - 1]) {
                int j = si[wv][e];
                d16[NCAND - 1] = dv; i16[NCAND - 1] = j;
                #pragma unroll
                for (int s = NCAND - 1; s > 0; --s)
                    if (d16[s] < d16[s - 1]) { SWAPF(d16[s], d16[s - 1]); SWAPI(i16[s], i16[s - 1]); }
            }
        }
        #pragma unroll
        for (int s = 0; s < NCAND; ++s)
            cand[(size_t)row * NCAND + s] = i16[s];
    }
}

// Phase 2 (UNCHANGED from passing R4): bit-replicate the numpy fp32 pipeline
// on the 16 candidates; top-4 by (q, index); z_q/loss/ste/k_hot.
__global__ void rescore_kernel(const float* __restrict__ ze,
                               const float* __restrict__ cb,
                               const int* __restrict__ cand,
                               float* __restrict__ out_zq,
                               float* __restrict__ out_khot,
                               double* __restrict__ lossAcc) {
    __shared__ float zsh[4][DIM];
    const int wv = threadIdx.x >> 6;
    const int lane = threadIdx.x & 63;
    const int row = blockIdx.x * 4 + wv;

    {
        const float* zp = ze + (size_t)row * DIM + lane * 8;
        float4 v0 = *(const float4*)zp;
        float4 v1 = *(const float4*)(zp + 4);
        *(float4*)&zsh[wv][lane * 8]     = v0;
        *(float4*)&zsh[wv][lane * 8 + 4] = v1;
    }
    __syncthreads();

    // znorm, numpy-pairwise
    float racc = 0.0f;
    {
        const int b = (lane >> 3) & 3;
        const int j = lane & 7;
        const float* zr = &zsh[wv][128 * b + j];
        #pragma unroll
        for (int i = 0; i < 16; ++i) {
            float zk = zr[8 * i];
            float sq = zk * zk;
            asm volatile("" : "+v"(sq));   // block FMA contraction into the add
            racc = racc + sq;
        }
    }
    float t1 = racc + __shfl_xor(racc, 1, 64);
    float t2 = t1 + __shfl_xor(t1, 2, 64);
    float t3 = t2 + __shfl_xor(t2, 4, 64);
    float zn = (__shfl(t3, 0, 64) + __shfl(t3, 8, 64))
             + (__shfl(t3, 16, 64) + __shfl(t3, 24, 64));

    // candidate chains: KC=384 split, sequential FMA, single accumulator each
    float qv = 3.0e38f;
    int   idxv = 0x7fffffff;
    if (lane < NCAND) {
        idxv = cand[(size_t)row * NCAND + lane];
        const float* wp = cb + (size_t)idxv * DIM;
        const float* zz = zsh[wv];
        float acc1 = 0.0f;
        for (int k = 0; k < 384; k += 8) {
            float4 wa = *(const float4*)(wp + k);
            float4 wb = *(const float4*)(wp + k + 4);
            acc1 = __builtin_fmaf(zz[k + 0], wa.x, acc1);
            acc1 = __builtin_fmaf(zz[k + 1], wa.y, acc1);
            acc1 = __builtin_fmaf(zz[k + 2], wa.z, acc1);
            acc1 = __builtin_fmaf(zz[k + 3], wa.w, acc1);
            acc1 = __builtin_fmaf(zz[k + 4], wb.x, acc1);
            acc1 = __builtin_fmaf(zz[k + 5], wb.y, acc1);
            acc1 = __builtin_fmaf(zz[k + 6], wb.z, acc1);
            acc1 = __builtin_fmaf(zz[k + 7], wb.w, acc1);
        }
        float acc2 = 0.0f;
        for (int k = 384; k < 512; k += 8) {
            float4 wa = *(const float4*)(wp + k);
            float4 wb = *(const float4*)(wp + k + 4);
            acc2 = __builtin_fmaf(zz[k + 0], wa.x, acc2);
            acc2 = __builtin_fmaf(zz[k + 1], wa.y, acc2);
            acc2 = __builtin_fmaf(zz[k + 2], wa.z, acc2);
            acc2 = __builtin_fmaf(zz[k + 3], wa.w, acc2);
            acc2 = __builtin_fmaf(zz[k + 4], wb.x, acc2);
            acc2 = __builtin_fmaf(zz[k + 5], wb.y, acc2);
            acc2 = __builtin_fmaf(zz[k + 6], wb.z, acc2);
            acc2 = __builtin_fmaf(zz[k + 7], wb.w, acc2);
        }
        float Cv = acc1 + acc2;
        qv = zn - 2.0f * Cv;
    }

    float q[NCAND]; int id[NCAND];
    #pragma unroll
    for (int c = 0; c < NCAND; ++c) {
        q[c]  = __shfl(qv, c, 64);
        id[c] = __shfl(idxv, c, 64);
    }
    int selIdx[4];
    bool used[NCAND];
    #pragma unroll
    for (int c = 0; c < NCAND; ++c) used[c] = false;
    #pragma unroll
    for (int s = 0; s < 4; ++s) {
        float bq = 3.0e38f; int bi = 0x7fffffff; int bc = -1;
        #pragma unroll
        for (int c = 0; c < NCAND; ++c) {
            bool better = !used[c] && (q[c] < bq || (q[c] == bq && id[c] < bi));
            if (better) { bq = q[c]; bi = id[c]; bc = c; }
        }
        selIdx[s] = bi;
        #pragma unroll
        for (int c = 0; c < NCAND; ++c) used[c] = used[c] || (c == bc);
    }

    float zq[8] = { 0, 0, 0, 0, 0, 0, 0, 0 };
    #pragma unroll
    for (int s = 0; s < 4; ++s) {
        const float* wp = cb + (size_t)selIdx[s] * DIM + lane * 8;
        float4 w0 = *(const float4*)wp;
        float4 w1 = *(const float4*)(wp + 4);
        zq[0] += w0.x; zq[1] += w0.y; zq[2] += w0.z; zq[3] += w0.w;
        zq[4] += w1.x; zq[5] += w1.y; zq[6] += w1.z; zq[7] += w1.w;
    }

    float zf[8];
    {
        const float* zz = &zsh[wv][lane * 8];
        #pragma unroll
        for (int i = 0; i < 8; ++i) zf[i] = zz[i];
    }
    float o[8];
    double l = 0.0;
    #pragma unroll
    for (int i = 0; i < 8; ++i) {
        float zqf  = zq[i] * 0.25f;
        float diff = zqf - zf[i];
        o[i] = zf[i] + diff;
        double ld = (double)diff;
        l += ld * ld;
    }
    {
        float* op = out_zq + (size_t)row * DIM + lane * 8;
        float4 v0 = { o[0], o[1], o[2], o[3] };
        float4 v1 = { o[4], o[5], o[6], o[7] };
        *(float4*)op = v0;
        *(float4*)(op + 4) = v1;
    }
    #pragma unroll
    for (int m = 32; m; m >>= 1) l += __shfl_xor(l, m, 64);
    if (lane == 0) atomicAdd(lossAcc, l);

    if (lane < 4)
        out_khot[(size_t)row * N_EMB + selIdx[lane]] = 1.0f;
}

__global__ void finalize_kernel(const double* __restrict__ lossAcc,
                                float* __restrict__ out_loss) {
    if (threadIdx.x == 0 && blockIdx.x == 0)
        out_loss[0] = (float)(lossAcc[0] * (1.25 / ((double)N_ROWS * (double)DIM)));
}

extern "C" void kernel_launch(void* const* d_in, const int* in_sizes, int n_in,
                              void* d_out, int out_size, void* d_ws, size_t ws_size,
                              hipStream_t stream) {
    (void)in_sizes; (void)n_in; (void)out_size; (void)ws_size;
    const float* ze = (const float*)d_in[0];
    const float* cb = (const float*)d_in[1];

    float* out      = (float*)d_out;
    float* out_zq   = out;                                   // [16384, 512]
    float* out_loss = out + (size_t)N_ROWS * DIM;            // [1]
    float* out_khot = out_loss + 1;                          // [16384, 8192]

    double* lossAcc = (double*)d_ws;
    int*    cand    = (int*)((char*)d_ws + 16);

    float* scores = out_khot;   // 512 MB scratch, consumed before zeroing

    hipMemsetAsync(lossAcc, 0, 16, stream);

    score_gemm_kernel<<<dim3(N_EMB / 128, N_ROWS / 128), 256, 0, stream>>>(ze, cb, scores);
    topk_scan_kernel<<<N_ROWS / 4, 256, 0, stream>>>(scores, cand);
    hipMemsetAsync(out_khot, 0, (size_t)N_ROWS * N_EMB * sizeof(float), stream);
    rescore_kernel<<<N_ROWS / 4, 256, 0, stream>>>(ze, cb, cand, out_zq, out_khot, lossAcc);
    finalize_kernel<<<1, 64, 0, stream>>>(lossAcc, out_loss);
}

// Round 6
// 1169.617 us; speedup vs baseline: 5.6194x; 1.6316x over previous
//
#include <hip/hip_runtime.h>

#define N_ROWS 16384
#define N_EMB  8192
#define DIM    512
#define NCAND  16

// ---------------------------------------------------------------------------
// ws layout:
//   [0]    double lossAcc (16 B, zeroed)
//   [16]   int cand[N_ROWS * NCAND]   (1 MB)
// k_hot region (512 MB at d_out + 33554436 B) is used as scratch BEFORE its
// memset:  +12 B        : sortable-bf16 score keys u16[N_ROWS*N_EMB] (256 MB)
//          +12+256 MB   : ze_bf16  u16[N_ROWS*DIM]  (16.8 MB)
//          then         : cb_bf16  u16[N_EMB*DIM]   ( 8.4 MB)
// All offsets keep 16-byte alignment. Total < 512 MB.
// ---------------------------------------------------------------------------

typedef short  bhalf8  __attribute__((ext_vector_type(8)));
typedef float  floatx4 __attribute__((ext_vector_type(4)));

__device__ __forceinline__ unsigned short f2b(float f) {
    unsigned u = __builtin_bit_cast(unsigned, f);
    unsigned r = (u + 0x7fffu + ((u >> 16) & 1u)) >> 16;   // RNE
    return (unsigned short)r;
}
__device__ __forceinline__ unsigned pk2(float a, float b) {
    return (unsigned)f2b(a) | ((unsigned)f2b(b) << 16);
}

// fp32 -> bf16 one-time conversion of both inputs (8 elements/thread).
__global__ void convert_bf16_kernel(const float* __restrict__ ze,
                                    const float* __restrict__ cb,
                                    unsigned short* __restrict__ ze16,
                                    unsigned short* __restrict__ cb16) {
    size_t id = (size_t)blockIdx.x * 256 + threadIdx.x;
    const size_t nze = (size_t)N_ROWS * DIM / 8;
    const float* src;
    unsigned short* dst;
    size_t off;
    if (id < nze) { src = ze; dst = ze16; off = id * 8; }
    else          { src = cb; dst = cb16; off = (id - nze) * 8; }
    float4 a = *(const float4*)(src + off);
    float4 b = *(const float4*)(src + off + 4);
    uint4 u = { pk2(a.x, a.y), pk2(a.z, a.w), pk2(b.x, b.y), pk2(b.z, b.w) };
    *(uint4*)(dst + off) = u;
}

// Phase 1a: bf16 MFMA GEMM. Writes sortable-bf16 keys of score = -(z.cb^T).
// 128x128 tile, BK=32, 16x16x32 MFMA, 4 waves as 2x2 of 64x64.
__launch_bounds__(256, 2)
__global__ void score_gemm_kernel(const unsigned short* __restrict__ ze16,
                                  const unsigned short* __restrict__ cb16,
                                  unsigned short* __restrict__ skeys) {
    __shared__ unsigned short As[128][40];   // 10 KB, 80 B row stride (16B-aligned frags)
    __shared__ unsigned short Bs[128][40];

    const int t    = threadIdx.x;
    const int lane = t & 63;
    const int w    = t >> 6;
    const int rowBase = blockIdx.y * 128;
    const int colBase = blockIdx.x * 128;

    const int m  = lane & 15;
    const int q  = lane >> 4;
    const int wr = (w >> 1) * 64;
    const int wc = (w & 1) * 64;

    floatx4 acc[4][4];
    #pragma unroll
    for (int i = 0; i < 4; ++i)
        #pragma unroll
        for (int j = 0; j < 4; ++j)
            acc[i][j] = (floatx4){0.0f, 0.0f, 0.0f, 0.0f};

    const int sr = t >> 1;          // staging row 0..127
    const int sk = (t & 1) * 16;    // staging k offset 0 or 16
    const unsigned short* pa = ze16 + (size_t)(rowBase + sr) * DIM + sk;
    const unsigned short* pb = cb16 + (size_t)(colBase + sr) * DIM + sk;

    for (int k0 = 0; k0 < DIM; k0 += 32) {
        // prefetch into registers while LDS still in use
        uint4 va0 = *(const uint4*)(pa + k0);
        uint4 va1 = *(const uint4*)(pa + k0 + 8);
        uint4 vb0 = *(const uint4*)(pb + k0);
        uint4 vb1 = *(const uint4*)(pb + k0 + 8);
        __syncthreads();
        *(uint4*)&As[sr][sk]     = va0;
        *(uint4*)&As[sr][sk + 8] = va1;
        *(uint4*)&Bs[sr][sk]     = vb0;
        *(uint4*)&Bs[sr][sk + 8] = vb1;
        __syncthreads();

        bhalf8 af[4], bf[4];
        #pragma unroll
        for (int i = 0; i < 4; ++i) af[i] = *(bhalf8*)&As[wr + i * 16 + m][q * 8];
        #pragma unroll
        for (int j = 0; j < 4; ++j) bf[j] = *(bhalf8*)&Bs[wc + j * 16 + m][q * 8];
        #pragma unroll
        for (int i = 0; i < 4; ++i)
            #pragma unroll
            for (int j = 0; j < 4; ++j)
                acc[i][j] = __builtin_amdgcn_mfma_f32_16x16x32_bf16(af[i], bf[j], acc[i][j], 0, 0, 0);
    }

    // epilogue: score = -C, bf16 RNE, sortable-u16 transform, scatter stores.
    // C/D layout: col = lane&15, row = quad*4 + reg.
    #pragma unroll
    for (int i = 0; i < 4; ++i) {
        #pragma unroll
        for (int reg = 0; reg < 4; ++reg) {
            int grow = rowBase + wr + i * 16 + q * 4 + reg;
            unsigned short* sp = skeys + (size_t)grow * N_EMB + colBase + wc + m;
            #pragma unroll
            for (int j = 0; j < 4; ++j) {
                unsigned short b = f2b(-acc[i][j][reg]);
                unsigned short s = (unsigned short)(b ^ ((b & 0x8000u) ? 0xFFFFu : 0x8000u));
                sp[j * 16] = s;
            }
        }
    }
}

// Phase 1b: wave-per-row scan of sortable keys -> per-row top-16 candidates.
// key = (sortable_bf16 << 16) | col : u32 ascending == (score, col) ascending.
// Branchless per-lane top-8 bubble (v_min/v_max), then 16 wave-min extractions.
__global__ void topk_scan_kernel(const unsigned short* __restrict__ skeys,
                                 int* __restrict__ cand) {
    const int wv   = threadIdx.x >> 6;
    const int lane = threadIdx.x & 63;
    const int row  = blockIdx.x * 4 + wv;
    const uint4* base = (const uint4*)(skeys + (size_t)row * N_EMB);

    unsigned k8[8];
    #pragma unroll
    for (int s = 0; s < 8; ++s) k8[s] = 0xFFFFFFFFu;

    auto ins = [&](unsigned e) {
        #pragma unroll
        for (int s = 0; s < 8; ++s) {
            unsigned lo = k8[s] < e ? k8[s] : e;
            unsigned hi = k8[s] < e ? e : k8[s];
            k8[s] = lo; e = hi;
        }
    };

    for (int it = 0; it < 16; ++it) {
        uint4 v = base[it * 64 + lane];
        unsigned colb = (unsigned)(it * 64 + lane) * 8;
        ins((v.x << 16) | (colb + 0)); ins((v.x & 0xFFFF0000u) | (colb + 1));
        ins((v.y << 16) | (colb + 2)); ins((v.y & 0xFFFF0000u) | (colb + 3));
        ins((v.z << 16) | (colb + 4)); ins((v.z & 0xFFFF0000u) | (colb + 5));
        ins((v.w << 16) | (colb + 6)); ins((v.w & 0xFFFF0000u) | (colb + 7));
    }

    // 16 rounds of wave-min extraction (keys unique: col is unique).
    unsigned win[NCAND];
    #pragma unroll
    for (int s = 0; s < NCAND; ++s) {
        unsigned mk = k8[0];
        #pragma unroll
        for (int d = 32; d; d >>= 1) {
            unsigned o = __shfl_xor(mk, d, 64);
            mk = o < mk ? o : mk;
        }
        win[s] = mk;
        bool pop = (k8[0] == mk);
        #pragma unroll
        for (int u = 0; u < 7; ++u) k8[u] = pop ? k8[u + 1] : k8[u];
        k8[7] = pop ? 0xFFFFFFFFu : k8[7];
    }

    if (lane == 0) {
        int* cp = cand + (size_t)row * NCAND;
        int4 o0 = { (int)(win[0] & 0xFFFFu),  (int)(win[1] & 0xFFFFu),
                    (int)(win[2] & 0xFFFFu),  (int)(win[3] & 0xFFFFu) };
        int4 o1 = { (int)(win[4] & 0xFFFFu),  (int)(win[5] & 0xFFFFu),
                    (int)(win[6] & 0xFFFFu),  (int)(win[7] & 0xFFFFu) };
        int4 o2 = { (int)(win[8] & 0xFFFFu),  (int)(win[9] & 0xFFFFu),
                    (int)(win[10] & 0xFFFFu), (int)(win[11] & 0xFFFFu) };
        int4 o3 = { (int)(win[12] & 0xFFFFu), (int)(win[13] & 0xFFFFu),
                    (int)(win[14] & 0xFFFFu), (int)(win[15] & 0xFFFFu) };
        *(int4*)(cp + 0)  = o0;
        *(int4*)(cp + 4)  = o1;
        *(int4*)(cp + 8)  = o2;
        *(int4*)(cp + 12) = o3;
    }
}

// Phase 2 (UNCHANGED, passing since R4): bit-replicate the numpy fp32 pipeline
// on the 16 candidates; top-4 by (q, index); z_q/loss/ste/k_hot.
__global__ void rescore_kernel(const float* __restrict__ ze,
                               const float* __restrict__ cb,
                               const int* __restrict__ cand,
                               float* __restrict__ out_zq,
                               float* __restrict__ out_khot,
                               double* __restrict__ lossAcc) {
    __shared__ float zsh[4][DIM];
    const int wv = threadIdx.x >> 6;
    const int lane = threadIdx.x & 63;
    const int row = blockIdx.x * 4 + wv;

    {
        const float* zp = ze + (size_t)row * DIM + lane * 8;
        float4 v0 = *(const float4*)zp;
        float4 v1 = *(const float4*)(zp + 4);
        *(float4*)&zsh[wv][lane * 8]     = v0;
        *(float4*)&zsh[wv][lane * 8 + 4] = v1;
    }
    __syncthreads();

    // znorm, numpy-pairwise
    float racc = 0.0f;
    {
        const int b = (lane >> 3) & 3;
        const int j = lane & 7;
        const float* zr = &zsh[wv][128 * b + j];
        #pragma unroll
        for (int i = 0; i < 16; ++i) {
            float zk = zr[8 * i];
            float sq = zk * zk;
            asm volatile("" : "+v"(sq));   // block FMA contraction into the add
            racc = racc + sq;
        }
    }
    float t1 = racc + __shfl_xor(racc, 1, 64);
    float t2 = t1 + __shfl_xor(t1, 2, 64);
    float t3 = t2 + __shfl_xor(t2, 4, 64);
    float zn = (__shfl(t3, 0, 64) + __shfl(t3, 8, 64))
             + (__shfl(t3, 16, 64) + __shfl(t3, 24, 64));

    // candidate chains: KC=384 split, sequential FMA, single accumulator each
    float qv = 3.0e38f;
    int   idxv = 0x7fffffff;
    if (lane < NCAND) {
        idxv = cand[(size_t)row * NCAND + lane];
        const float* wp = cb + (size_t)idxv * DIM;
        const float* zz = zsh[wv];
        float acc1 = 0.0f;
        for (int k = 0; k < 384; k += 8) {
            float4 wa = *(const float4*)(wp + k);
            float4 wb = *(const float4*)(wp + k + 4);
            acc1 = __builtin_fmaf(zz[k + 0], wa.x, acc1);
            acc1 = __builtin_fmaf(zz[k + 1], wa.y, acc1);
            acc1 = __builtin_fmaf(zz[k + 2], wa.z, acc1);
            acc1 = __builtin_fmaf(zz[k + 3], wa.w, acc1);
            acc1 = __builtin_fmaf(zz[k + 4], wb.x, acc1);
            acc1 = __builtin_fmaf(zz[k + 5], wb.y, acc1);
            acc1 = __builtin_fmaf(zz[k + 6], wb.z, acc1);
            acc1 = __builtin_fmaf(zz[k + 7], wb.w, acc1);
        }
        float acc2 = 0.0f;
        for (int k = 384; k < 512; k += 8) {
            float4 wa = *(const float4*)(wp + k);
            float4 wb = *(const float4*)(wp + k + 4);
            acc2 = __builtin_fmaf(zz[k + 0], wa.x, acc2);
            acc2 = __builtin_fmaf(zz[k + 1], wa.y, acc2);
            acc2 = __builtin_fmaf(zz[k + 2], wa.z, acc2);
            acc2 = __builtin_fmaf(zz[k + 3], wa.w, acc2);
            acc2 = __builtin_fmaf(zz[k + 4], wb.x, acc2);
            acc2 = __builtin_fmaf(zz[k + 5], wb.y, acc2);
            acc2 = __builtin_fmaf(zz[k + 6], wb.z, acc2);
            acc2 = __builtin_fmaf(zz[k + 7], wb.w, acc2);
        }
        float Cv = acc1 + acc2;
        qv = zn - 2.0f * Cv;
    }

    float q[NCAND]; int id[NCAND];
    #pragma unroll
    for (int c = 0; c < NCAND; ++c) {
        q[c]  = __shfl(qv, c, 64);
        id[c] = __shfl(idxv, c, 64);
    }
    int selIdx[4];
    bool used[NCAND];
    #pragma unroll
    for (int c = 0; c < NCAND; ++c) used[c] = false;
    #pragma unroll
    for (int s = 0; s < 4; ++s) {
        float bq = 3.0e38f; int bi = 0x7fffffff; int bc = -1;
        #pragma unroll
        for (int c = 0; c < NCAND; ++c) {
            bool better = !used[c] && (q[c] < bq || (q[c] == bq && id[c] < bi));
            if (better) { bq = q[c]; bi = id[c]; bc = c; }
        }
        selIdx[s] = bi;
        #pragma unroll
        for (int c = 0; c < NCAND; ++c) used[c] = used[c] || (c == bc);
    }

    float zq[8] = { 0, 0, 0, 0, 0, 0, 0, 0 };
    #pragma unroll
    for (int s = 0; s < 4; ++s) {
        const float* wp = cb + (size_t)selIdx[s] * DIM + lane * 8;
        float4 w0 = *(const float4*)wp;
        float4 w1 = *(const float4*)(wp + 4);
        zq[0] += w0.x; zq[1] += w0.y; zq[2] += w0.z; zq[3] += w0.w;
        zq[4] += w1.x; zq[5] += w1.y; zq[6] += w1.z; zq[7] += w1.w;
    }

    float zf[8];
    {
        const float* zz = &zsh[wv][lane * 8];
        #pragma unroll
        for (int i = 0; i < 8; ++i) zf[i] = zz[i];
    }
    float o[8];
    double l = 0.0;
    #pragma unroll
    for (int i = 0; i < 8; ++i) {
        float zqf  = zq[i] * 0.25f;
        float diff = zqf - zf[i];
        o[i] = zf[i] + diff;
        double ld = (double)diff;
        l += ld * ld;
    }
    {
        float* op = out_zq + (size_t)row * DIM + lane * 8;
        float4 v0 = { o[0], o[1], o[2], o[3] };
        float4 v1 = { o[4], o[5], o[6], o[7] };
        *(float4*)op = v0;
        *(float4*)(op + 4) = v1;
    }
    #pragma unroll
    for (int mm = 32; mm; mm >>= 1) l += __shfl_xor(l, mm, 64);
    if (lane == 0) atomicAdd(lossAcc, l);

    if (lane < 4)
        out_khot[(size_t)row * N_EMB + selIdx[lane]] = 1.0f;
}

__global__ void finalize_kernel(const double* __restrict__ lossAcc,
                                float* __restrict__ out_loss) {
    if (threadIdx.x == 0 && blockIdx.x == 0)
        out_loss[0] = (float)(lossAcc[0] * (1.25 / ((double)N_ROWS * (double)DIM)));
}

extern "C" void kernel_launch(void* const* d_in, const int* in_sizes, int n_in,
                              void* d_out, int out_size, void* d_ws, size_t ws_size,
                              hipStream_t stream) {
    (void)in_sizes; (void)n_in; (void)out_size; (void)ws_size;
    const float* ze = (const float*)d_in[0];
    const float* cb = (const float*)d_in[1];

    float* out      = (float*)d_out;
    float* out_zq   = out;                                   // [16384, 512]
    float* out_loss = out + (size_t)N_ROWS * DIM;            // [1]
    float* out_khot = out_loss + 1;                          // [16384, 8192]

    double* lossAcc = (double*)d_ws;
    int*    cand    = (int*)((char*)d_ws + 16);

    // scratch inside k_hot region, 16B-aligned, consumed before memset
    char* base = (char*)d_out;
    unsigned short* skeys = (unsigned short*)(base + 33554448);              // khot + 12 B
    unsigned short* ze16  = (unsigned short*)(base + 33554448 + 268435456);  // + 256 MB
    unsigned short* cb16  = ze16 + (size_t)N_ROWS * DIM;

    hipMemsetAsync(lossAcc, 0, 16, stream);

    convert_bf16_kernel<<<6144, 256, 0, stream>>>(ze, cb, ze16, cb16);
    score_gemm_kernel<<<dim3(N_EMB / 128, N_ROWS / 128), 256, 0, stream>>>(ze16, cb16, skeys);
    topk_scan_kernel<<<N_ROWS / 4, 256, 0, stream>>>(skeys, cand);
    hipMemsetAsync(out_khot, 0, (size_t)N_ROWS * N_EMB * sizeof(float), stream);
    rescore_kernel<<<N_ROWS / 4, 256, 0, stream>>>(ze, cb, cand, out_zq, out_khot, lossAcc);
    finalize_kernel<<<1, 64, 0, stream>>>(lossAcc, out_loss);
}

// Round 7
// 1116.850 us; speedup vs baseline: 5.8849x; 1.0472x over previous
//
#include <hip/hip_runtime.h>

#define N_ROWS 16384
#define N_EMB  8192
#define DIM    512
#define NCAND  16

// ---------------------------------------------------------------------------
// ws layout:
//   [0]    double lossAcc (16 B, zeroed)
//   [16]   int cand[N_ROWS * NCAND]   (1 MB)
// k_hot region (512 MB at d_out + 33554436 B) is scratch BEFORE its memset:
//   +12 B          : blkTop u32[N_ROWS*64*8]   (32 MB) per-block top-8 keys
//   +12+32 MB      : ze_bf16 u16[N_ROWS*DIM]   (16.8 MB)
//   then           : cb_bf16 u16[N_EMB*DIM]    ( 8.4 MB)
// All 16-byte aligned; consumed before the k_hot memset.
// ---------------------------------------------------------------------------

typedef short  bhalf8  __attribute__((ext_vector_type(8)));
typedef float  floatx4 __attribute__((ext_vector_type(4)));

__device__ __forceinline__ unsigned short f2b(float f) {
    unsigned u = __builtin_bit_cast(unsigned, f);
    unsigned r = (u + 0x7fffu + ((u >> 16) & 1u)) >> 16;   // RNE
    return (unsigned short)r;
}
__device__ __forceinline__ unsigned pk2(float a, float b) {
    return (unsigned)f2b(a) | ((unsigned)f2b(b) << 16);
}
// sortable key: ascending u32 == ascending (score, col); lower col wins ties
__device__ __forceinline__ unsigned mkkey(float s, int col) {
    unsigned short b = f2b(s);
    unsigned short ts = (unsigned short)(b ^ ((b & 0x8000u) ? 0xFFFFu : 0x8000u));
    return ((unsigned)ts << 16) | (unsigned)col;
}
__device__ __forceinline__ unsigned umn(unsigned a, unsigned b) { return a < b ? a : b; }

// fp32 -> bf16 one-time conversion of both inputs (8 elements/thread).
__global__ void convert_bf16_kernel(const float* __restrict__ ze,
                                    const float* __restrict__ cb,
                                    unsigned short* __restrict__ ze16,
                                    unsigned short* __restrict__ cb16) {
    size_t id = (size_t)blockIdx.x * 256 + threadIdx.x;
    const size_t nze = (size_t)N_ROWS * DIM / 8;
    const float* src;
    unsigned short* dst;
    size_t off;
    if (id < nze) { src = ze; dst = ze16; off = id * 8; }
    else          { src = cb; dst = cb16; off = (id - nze) * 8; }
    float4 a = *(const float4*)(src + off);
    float4 b = *(const float4*)(src + off + 4);
    uint4 u = { pk2(a.x, a.y), pk2(a.z, a.w), pk2(b.x, b.y), pk2(b.z, b.w) };
    *(uint4*)(dst + off) = u;
}

// Phase 1a: bf16 MFMA GEMM fused with per-block per-row top-8.
// 128x128 tile, BK=32. 4 waves = 4 row-stripes of 32 rows x 128 cols
// (acc[2][8]) so each wave owns complete rows. Epilogue: branchless
// per-lane sort-8 + 8 rounds of 16-lane-group min extraction.
__launch_bounds__(256, 3)
__global__ void score_gemm_topk_kernel(const unsigned short* __restrict__ ze16,
                                       const unsigned short* __restrict__ cb16,
                                       unsigned* __restrict__ blkTop) {
    __shared__ unsigned short As[128][40];   // 10 KB, 80 B row stride
    __shared__ unsigned short Bs[128][40];

    const int t    = threadIdx.x;
    const int lane = t & 63;
    const int w    = t >> 6;
    const int rowBase = blockIdx.y * 128;
    const int colBase = blockIdx.x * 128;
    const int cblk    = blockIdx.x;

    const int m = lane & 15;
    const int q = lane >> 4;

    floatx4 acc[2][8];
    #pragma unroll
    for (int i = 0; i < 2; ++i)
        #pragma unroll
        for (int j = 0; j < 8; ++j)
            acc[i][j] = (floatx4){0.0f, 0.0f, 0.0f, 0.0f};

    const int sr = t >> 1;          // staging row 0..127
    const int sk = (t & 1) * 16;    // staging k offset 0 or 16
    const unsigned short* pa = ze16 + (size_t)(rowBase + sr) * DIM + sk;
    const unsigned short* pb = cb16 + (size_t)(colBase + sr) * DIM + sk;

    for (int k0 = 0; k0 < DIM; k0 += 32) {
        uint4 va0 = *(const uint4*)(pa + k0);
        uint4 va1 = *(const uint4*)(pa + k0 + 8);
        uint4 vb0 = *(const uint4*)(pb + k0);
        uint4 vb1 = *(const uint4*)(pb + k0 + 8);
        __syncthreads();
        *(uint4*)&As[sr][sk]     = va0;
        *(uint4*)&As[sr][sk + 8] = va1;
        *(uint4*)&Bs[sr][sk]     = vb0;
        *(uint4*)&Bs[sr][sk + 8] = vb1;
        __syncthreads();

        bhalf8 af0 = *(bhalf8*)&As[w * 32 + m][q * 8];
        bhalf8 af1 = *(bhalf8*)&As[w * 32 + 16 + m][q * 8];
        #pragma unroll
        for (int j = 0; j < 8; ++j) {
            bhalf8 bf = *(bhalf8*)&Bs[j * 16 + m][q * 8];
            acc[0][j] = __builtin_amdgcn_mfma_f32_16x16x32_bf16(af0, bf, acc[0][j], 0, 0, 0);
            acc[1][j] = __builtin_amdgcn_mfma_f32_16x16x32_bf16(af1, bf, acc[1][j], 0, 0, 0);
        }
    }

    // Epilogue. C/D layout: col = lane&15, row = quad*4 + reg.
    #pragma unroll
    for (int i = 0; i < 2; ++i) {
        #pragma unroll
        for (int reg = 0; reg < 4; ++reg) {
            const int grow = rowBase + w * 32 + i * 16 + q * 4 + reg;
            unsigned kk[8];
            #pragma unroll
            for (int j = 0; j < 8; ++j) {
                unsigned e = mkkey(-acc[i][j][reg], colBase + j * 16 + m);
                kk[j] = e;
                #pragma unroll
                for (int s = 7; s > 0; --s) {
                    if (s <= j) {
                        unsigned lo = umn(kk[s - 1], kk[s]);
                        unsigned hi = kk[s - 1] < kk[s] ? kk[s] : kk[s - 1];
                        kk[s - 1] = lo; kk[s] = hi;
                    }
                }
            }
            unsigned sval = 0;
            #pragma unroll
            for (int s = 0; s < 8; ++s) {
                unsigned g = kk[0];
                g = umn(g, (unsigned)__shfl_xor((int)g, 1, 64));
                g = umn(g, (unsigned)__shfl_xor((int)g, 2, 64));
                g = umn(g, (unsigned)__shfl_xor((int)g, 4, 64));
                g = umn(g, (unsigned)__shfl_xor((int)g, 8, 64));
                bool pop = (kk[0] == g);
                #pragma unroll
                for (int u = 0; u < 7; ++u) kk[u] = pop ? kk[u + 1] : kk[u];
                kk[7] = pop ? 0xFFFFFFFFu : kk[7];
                sval = (m == s) ? g : sval;
            }
            if (m < 8)
                blkTop[((size_t)grow * 64 + cblk) * 8 + m] = sval;
        }
    }
}

// Phase 1b: merge 64 blocks x 8 keys per row -> top-16 candidates.
// One wave per row; 8 keys/lane; per-lane sort-8 + 16 wave-min extractions.
__global__ void merge_topk_kernel(const unsigned* __restrict__ blkTop,
                                  int* __restrict__ cand) {
    const int wv   = threadIdx.x >> 6;
    const int lane = threadIdx.x & 63;
    const int row  = blockIdx.x * 4 + wv;
    const uint4* base = (const uint4*)(blkTop + (size_t)row * 512);

    uint4 a = base[lane * 2];
    uint4 b = base[lane * 2 + 1];
    unsigned in[8] = { a.x, a.y, a.z, a.w, b.x, b.y, b.z, b.w };
    unsigned kk[8];
    #pragma unroll
    for (int j = 0; j < 8; ++j) {
        kk[j] = in[j];
        #pragma unroll
        for (int s = 7; s > 0; --s) {
            if (s <= j) {
                unsigned lo = umn(kk[s - 1], kk[s]);
                unsigned hi = kk[s - 1] < kk[s] ? kk[s] : kk[s - 1];
                kk[s - 1] = lo; kk[s] = hi;
            }
        }
    }

    unsigned sval = 0;
    #pragma unroll
    for (int s = 0; s < NCAND; ++s) {
        unsigned g = kk[0];
        #pragma unroll
        for (int d = 32; d; d >>= 1)
            g = umn(g, (unsigned)__shfl_xor((int)g, d, 64));
        bool pop = (kk[0] == g);
        #pragma unroll
        for (int u = 0; u < 7; ++u) kk[u] = pop ? kk[u + 1] : kk[u];
        kk[7] = pop ? 0xFFFFFFFFu : kk[7];
        sval = (lane == s) ? g : sval;
    }
    if (lane < NCAND)
        cand[(size_t)row * NCAND + lane] = (int)(sval & 0xFFFFu);
}

// Phase 2 (UNCHANGED, passing since R4): bit-replicate the numpy fp32 pipeline
// on the 16 candidates; top-4 by (q, index); z_q/loss/ste/k_hot.
__global__ void rescore_kernel(const float* __restrict__ ze,
                               const float* __restrict__ cb,
                               const int* __restrict__ cand,
                               float* __restrict__ out_zq,
                               float* __restrict__ out_khot,
                               double* __restrict__ lossAcc) {
    __shared__ float zsh[4][DIM];
    const int wv = threadIdx.x >> 6;
    const int lane = threadIdx.x & 63;
    const int row = blockIdx.x * 4 + wv;

    {
        const float* zp = ze + (size_t)row * DIM + lane * 8;
        float4 v0 = *(const float4*)zp;
        float4 v1 = *(const float4*)(zp + 4);
        *(float4*)&zsh[wv][lane * 8]     = v0;
        *(float4*)&zsh[wv][lane * 8 + 4] = v1;
    }
    __syncthreads();

    // znorm, numpy-pairwise
    float racc = 0.0f;
    {
        const int b = (lane >> 3) & 3;
        const int j = lane & 7;
        const float* zr = &zsh[wv][128 * b + j];
        #pragma unroll
        for (int i = 0; i < 16; ++i) {
            float zk = zr[8 * i];
            float sq = zk * zk;
            asm volatile("" : "+v"(sq));   // block FMA contraction into the add
            racc = racc + sq;
        }
    }
    float t1 = racc + __shfl_xor(racc, 1, 64);
    float t2 = t1 + __shfl_xor(t1, 2, 64);
    float t3 = t2 + __shfl_xor(t2, 4, 64);
    float zn = (__shfl(t3, 0, 64) + __shfl(t3, 8, 64))
             + (__shfl(t3, 16, 64) + __shfl(t3, 24, 64));

    // candidate chains: KC=384 split, sequential FMA, single accumulator each
    float qv = 3.0e38f;
    int   idxv = 0x7fffffff;
    if (lane < NCAND) {
        idxv = cand[(size_t)row * NCAND + lane];
        const float* wp = cb + (size_t)idxv * DIM;
        const float* zz = zsh[wv];
        float acc1 = 0.0f;
        for (int k = 0; k < 384; k += 8) {
            float4 wa = *(const float4*)(wp + k);
            float4 wb = *(const float4*)(wp + k + 4);
            acc1 = __builtin_fmaf(zz[k + 0], wa.x, acc1);
            acc1 = __builtin_fmaf(zz[k + 1], wa.y, acc1);
            acc1 = __builtin_fmaf(zz[k + 2], wa.z, acc1);
            acc1 = __builtin_fmaf(zz[k + 3], wa.w, acc1);
            acc1 = __builtin_fmaf(zz[k + 4], wb.x, acc1);
            acc1 = __builtin_fmaf(zz[k + 5], wb.y, acc1);
            acc1 = __builtin_fmaf(zz[k + 6], wb.z, acc1);
            acc1 = __builtin_fmaf(zz[k + 7], wb.w, acc1);
        }
        float acc2 = 0.0f;
        for (int k = 384; k < 512; k += 8) {
            float4 wa = *(const float4*)(wp + k);
            float4 wb = *(const float4*)(wp + k + 4);
            acc2 = __builtin_fmaf(zz[k + 0], wa.x, acc2);
            acc2 = __builtin_fmaf(zz[k + 1], wa.y, acc2);
            acc2 = __builtin_fmaf(zz[k + 2], wa.z, acc2);
            acc2 = __builtin_fmaf(zz[k + 3], wa.w, acc2);
            acc2 = __builtin_fmaf(zz[k + 4], wb.x, acc2);
            acc2 = __builtin_fmaf(zz[k + 5], wb.y, acc2);
            acc2 = __builtin_fmaf(zz[k + 6], wb.z, acc2);
            acc2 = __builtin_fmaf(zz[k + 7], wb.w, acc2);
        }
        float Cv = acc1 + acc2;
        qv = zn - 2.0f * Cv;
    }

    float q[NCAND]; int id[NCAND];
    #pragma unroll
    for (int c = 0; c < NCAND; ++c) {
        q[c]  = __shfl(qv, c, 64);
        id[c] = __shfl(idxv, c, 64);
    }
    int selIdx[4];
    bool used[NCAND];
    #pragma unroll
    for (int c = 0; c < NCAND; ++c) used[c] = false;
    #pragma unroll
    for (int s = 0; s < 4; ++s) {
        float bq = 3.0e38f; int bi = 0x7fffffff; int bc = -1;
        #pragma unroll
        for (int c = 0; c < NCAND; ++c) {
            bool better = !used[c] && (q[c] < bq || (q[c] == bq && id[c] < bi));
            if (better) { bq = q[c]; bi = id[c]; bc = c; }
        }
        selIdx[s] = bi;
        #pragma unroll
        for (int c = 0; c < NCAND; ++c) used[c] = used[c] || (c == bc);
    }

    float zq[8] = { 0, 0, 0, 0, 0, 0, 0, 0 };
    #pragma unroll
    for (int s = 0; s < 4; ++s) {
        const float* wp = cb + (size_t)selIdx[s] * DIM + lane * 8;
        float4 w0 = *(const float4*)wp;
        float4 w1 = *(const float4*)(wp + 4);
        zq[0] += w0.x; zq[1] += w0.y; zq[2] += w0.z; zq[3] += w0.w;
        zq[4] += w1.x; zq[5] += w1.y; zq[6] += w1.z; zq[7] += w1.w;
    }

    float zf[8];
    {
        const float* zz = &zsh[wv][lane * 8];
        #pragma unroll
        for (int i = 0; i < 8; ++i) zf[i] = zz[i];
    }
    float o[8];
    double l = 0.0;
    #pragma unroll
    for (int i = 0; i < 8; ++i) {
        float zqf  = zq[i] * 0.25f;
        float diff = zqf - zf[i];
        o[i] = zf[i] + diff;
        double ld = (double)diff;
        l += ld * ld;
    }
    {
        float* op = out_zq + (size_t)row * DIM + lane * 8;
        float4 v0 = { o[0], o[1], o[2], o[3] };
        float4 v1 = { o[4], o[5], o[6], o[7] };
        *(float4*)op = v0;
        *(float4*)(op + 4) = v1;
    }
    #pragma unroll
    for (int mm = 32; mm; mm >>= 1) l += __shfl_xor(l, mm, 64);
    if (lane == 0) atomicAdd(lossAcc, l);

    if (lane < 4)
        out_khot[(size_t)row * N_EMB + selIdx[lane]] = 1.0f;
}

__global__ void finalize_kernel(const double* __restrict__ lossAcc,
                                float* __restrict__ out_loss) {
    if (threadIdx.x == 0 && blockIdx.x == 0)
        out_loss[0] = (float)(lossAcc[0] * (1.25 / ((double)N_ROWS * (double)DIM)));
}

extern "C" void kernel_launch(void* const* d_in, const int* in_sizes, int n_in,
                              void* d_out, int out_size, void* d_ws, size_t ws_size,
                              hipStream_t stream) {
    (void)in_sizes; (void)n_in; (void)out_size; (void)ws_size;
    const float* ze = (const float*)d_in[0];
    const float* cb = (const float*)d_in[1];

    float* out      = (float*)d_out;
    float* out_zq   = out;                                   // [16384, 512]
    float* out_loss = out + (size_t)N_ROWS * DIM;            // [1]
    float* out_khot = out_loss + 1;                          // [16384, 8192]

    double* lossAcc = (double*)d_ws;
    int*    cand    = (int*)((char*)d_ws + 16);

    // scratch inside k_hot region, 16B-aligned, consumed before memset
    char* base = (char*)d_out;
    unsigned*       blkTop = (unsigned*)(base + 33554448);               // khot + 12 B
    unsigned short* ze16   = (unsigned short*)(base + 33554448 + 33554432); // + 32 MB
    unsigned short* cb16   = ze16 + (size_t)N_ROWS * DIM;

    hipMemsetAsync(lossAcc, 0, 16, stream);

    convert_bf16_kernel<<<6144, 256, 0, stream>>>(ze, cb, ze16, cb16);
    score_gemm_topk_kernel<<<dim3(N_EMB / 128, N_ROWS / 128), 256, 0, stream>>>(ze16, cb16, blkTop);
    merge_topk_kernel<<<N_ROWS / 4, 256, 0, stream>>>(blkTop, cand);
    hipMemsetAsync(out_khot, 0, (size_t)N_ROWS * N_EMB * sizeof(float), stream);
    rescore_kernel<<<N_ROWS / 4, 256, 0, stream>>>(ze, cb, cand, out_zq, out_khot, lossAcc);
    finalize_kernel<<<1, 64, 0, stream>>>(lossAcc, out_loss);
}

// Round 8
// 1113.903 us; speedup vs baseline: 5.9005x; 1.0026x over previous
//
#include <hip/hip_runtime.h>

#define N_ROWS 16384
#define N_EMB  8192
#define DIM    512
#define NCAND  16

#define GAS __attribute__((address_space(1)))
#define LAS __attribute__((address_space(3)))

// ---------------------------------------------------------------------------
// ws layout:
//   [0]    double lossAcc (16 B, zeroed)
//   [16]   int cand[N_ROWS * NCAND]   (1 MB)
// k_hot region (512 MB at d_out + 33554436 B) is scratch BEFORE its memset:
//   +12 B          : blkTop u32[N_ROWS*64*8]   (32 MB) per-block top-8 keys
//   +12+32 MB      : ze_bf16 u16[N_ROWS*DIM]   (16.8 MB)
//   then           : cb_bf16 u16[N_EMB*DIM]    ( 8.4 MB)
// All 16-byte aligned; consumed before the k_hot memset.
// ---------------------------------------------------------------------------

typedef short  bhalf8  __attribute__((ext_vector_type(8)));
typedef float  floatx4 __attribute__((ext_vector_type(4)));

__device__ __forceinline__ unsigned short f2b(float f) {
    unsigned u = __builtin_bit_cast(unsigned, f);
    unsigned r = (u + 0x7fffu + ((u >> 16) & 1u)) >> 16;   // RNE
    return (unsigned short)r;
}
__device__ __forceinline__ unsigned pk2(float a, float b) {
    return (unsigned)f2b(a) | ((unsigned)f2b(b) << 16);
}
// sortable key: ascending u32 == ascending (score, col); lower col wins ties
__device__ __forceinline__ unsigned mkkey(float s, int col) {
    unsigned short b = f2b(s);
    unsigned short ts = (unsigned short)(b ^ ((b & 0x8000u) ? 0xFFFFu : 0x8000u));
    return ((unsigned)ts << 16) | (unsigned)col;
}
__device__ __forceinline__ unsigned umn(unsigned a, unsigned b) { return a < b ? a : b; }

// fp32 -> bf16 one-time conversion of both inputs (8 elements/thread).
__global__ void convert_bf16_kernel(const float* __restrict__ ze,
                                    const float* __restrict__ cb,
                                    unsigned short* __restrict__ ze16,
                                    unsigned short* __restrict__ cb16) {
    size_t id = (size_t)blockIdx.x * 256 + threadIdx.x;
    const size_t nze = (size_t)N_ROWS * DIM / 8;
    const float* src;
    unsigned short* dst;
    size_t off;
    if (id < nze) { src = ze; dst = ze16; off = id * 8; }
    else          { src = cb; dst = cb16; off = (id - nze) * 8; }
    float4 a = *(const float4*)(src + off);
    float4 b = *(const float4*)(src + off + 4);
    uint4 u = { pk2(a.x, a.y), pk2(a.z, a.w), pk2(b.x, b.y), pk2(b.z, b.w) };
    *(uint4*)(dst + off) = u;
}

// Phase 1a: bf16 MFMA GEMM fused with per-block per-row top-8.
// 128x128 tile, BK=32. 4 waves = 4 row-stripes of 32 rows x 128 cols.
// Staging via global_load_lds width=16 (wave-uniform LDS base + lane*16):
// tile is unpadded row-major [128][32] bf16 (64 B rows); 16 B chunks are
// XOR-swizzled in the GLOBAL address (c_g = c_lds ^ ((row>>1)&3)) so the
// MFMA fragment reads hit all 8 bank-quads (2-way aliasing only = free).
__launch_bounds__(256, 3)
__global__ void score_gemm_topk_kernel(const unsigned short* __restrict__ ze16,
                                       const unsigned short* __restrict__ cb16,
                                       unsigned* __restrict__ blkTop) {
    __shared__ unsigned short Amm[128 * 32];   // 8 KB
    __shared__ unsigned short Bmm[128 * 32];   // 8 KB

    const int t    = threadIdx.x;
    const int lane = t & 63;
    const int w    = t >> 6;
    const int rowBase = blockIdx.y * 128;
    const int colBase = blockIdx.x * 128;
    const int cblk    = blockIdx.x;

    const int m = lane & 15;
    const int q = lane >> 4;

    floatx4 acc[2][8];
    #pragma unroll
    for (int i = 0; i < 2; ++i)
        #pragma unroll
        for (int j = 0; j < 8; ++j)
            acc[i][j] = (floatx4){0.0f, 0.0f, 0.0f, 0.0f};

    // staging: slot s = r*256 + t covers (row = s>>2, chunk c_lds = s&3);
    // global chunk c_g = c_lds ^ ((row>>1)&3) = (s&3) ^ ((s>>3)&3)
    const int s0 = t, s1 = t + 256;
    const int ar0 = s0 >> 2, ac0 = (s0 & 3) ^ ((s0 >> 3) & 3);
    const int ar1 = s1 >> 2, ac1 = (s1 & 3) ^ ((s1 >> 3) & 3);
    const unsigned short* pa0 = ze16 + (size_t)(rowBase + ar0) * DIM + ac0 * 8;
    const unsigned short* pa1 = ze16 + (size_t)(rowBase + ar1) * DIM + ac1 * 8;
    const unsigned short* pb0 = cb16 + (size_t)(colBase + ar0) * DIM + ac0 * 8;
    const unsigned short* pb1 = cb16 + (size_t)(colBase + ar1) * DIM + ac1 * 8;
    // wave-uniform LDS bases (elements): s_base*8, s_base = r*256 + w*64
    unsigned short* lA0 = Amm + (w * 64) * 8;
    unsigned short* lA1 = Amm + (256 + w * 64) * 8;
    unsigned short* lB0 = Bmm + (w * 64) * 8;
    unsigned short* lB1 = Bmm + (256 + w * 64) * 8;

    const int ch = (q ^ ((m >> 1) & 3)) * 8;   // swizzled chunk for frag reads

    for (int k0 = 0; k0 < DIM; k0 += 32) {
        __syncthreads();
        __builtin_amdgcn_global_load_lds((const GAS void*)(pa0 + k0), (LAS void*)lA0, 16, 0, 0);
        __builtin_amdgcn_global_load_lds((const GAS void*)(pa1 + k0), (LAS void*)lA1, 16, 0, 0);
        __builtin_amdgcn_global_load_lds((const GAS void*)(pb0 + k0), (LAS void*)lB0, 16, 0, 0);
        __builtin_amdgcn_global_load_lds((const GAS void*)(pb1 + k0), (LAS void*)lB1, 16, 0, 0);
        __syncthreads();

        bhalf8 af0 = *(bhalf8*)&Amm[(w * 32 + m) * 32 + ch];
        bhalf8 af1 = *(bhalf8*)&Amm[(w * 32 + 16 + m) * 32 + ch];
        #pragma unroll
        for (int j = 0; j < 8; ++j) {
            bhalf8 bf = *(bhalf8*)&Bmm[(j * 16 + m) * 32 + ch];
            acc[0][j] = __builtin_amdgcn_mfma_f32_16x16x32_bf16(af0, bf, acc[0][j], 0, 0, 0);
            acc[1][j] = __builtin_amdgcn_mfma_f32_16x16x32_bf16(af1, bf, acc[1][j], 0, 0, 0);
        }
    }

    // Epilogue (proven R7). C/D layout: col = lane&15, row = quad*4 + reg.
    #pragma unroll
    for (int i = 0; i < 2; ++i) {
        #pragma unroll
        for (int reg = 0; reg < 4; ++reg) {
            const int grow = rowBase + w * 32 + i * 16 + q * 4 + reg;
            unsigned kk[8];
            #pragma unroll
            for (int j = 0; j < 8; ++j) {
                unsigned e = mkkey(-acc[i][j][reg], colBase + j * 16 + m);
                kk[j] = e;
                #pragma unroll
                for (int s = 7; s > 0; --s) {
                    if (s <= j) {
                        unsigned lo = umn(kk[s - 1], kk[s]);
                        unsigned hi = kk[s - 1] < kk[s] ? kk[s] : kk[s - 1];
                        kk[s - 1] = lo; kk[s] = hi;
                    }
                }
            }
            unsigned sval = 0;
            #pragma unroll
            for (int s = 0; s < 8; ++s) {
                unsigned g = kk[0];
                g = umn(g, (unsigned)__shfl_xor((int)g, 1, 64));
                g = umn(g, (unsigned)__shfl_xor((int)g, 2, 64));
                g = umn(g, (unsigned)__shfl_xor((int)g, 4, 64));
                g = umn(g, (unsigned)__shfl_xor((int)g, 8, 64));
                bool pop = (kk[0] == g);
                #pragma unroll
                for (int u = 0; u < 7; ++u) kk[u] = pop ? kk[u + 1] : kk[u];
                kk[7] = pop ? 0xFFFFFFFFu : kk[7];
                sval = (m == s) ? g : sval;
            }
            if (m < 8)
                blkTop[((size_t)grow * 64 + cblk) * 8 + m] = sval;
        }
    }
}

// Phase 1b: merge 64 blocks x 8 keys per row -> top-16 candidates.
__global__ void merge_topk_kernel(const unsigned* __restrict__ blkTop,
                                  int* __restrict__ cand) {
    const int wv   = threadIdx.x >> 6;
    const int lane = threadIdx.x & 63;
    const int row  = blockIdx.x * 4 + wv;
    const uint4* base = (const uint4*)(blkTop + (size_t)row * 512);

    uint4 a = base[lane * 2];
    uint4 b = base[lane * 2 + 1];
    unsigned in[8] = { a.x, a.y, a.z, a.w, b.x, b.y, b.z, b.w };
    unsigned kk[8];
    #pragma unroll
    for (int j = 0; j < 8; ++j) {
        kk[j] = in[j];
        #pragma unroll
        for (int s = 7; s > 0; --s) {
            if (s <= j) {
                unsigned lo = umn(kk[s - 1], kk[s]);
                unsigned hi = kk[s - 1] < kk[s] ? kk[s] : kk[s - 1];
                kk[s - 1] = lo; kk[s] = hi;
            }
        }
    }

    unsigned sval = 0;
    #pragma unroll
    for (int s = 0; s < NCAND; ++s) {
        unsigned g = kk[0];
        #pragma unroll
        for (int d = 32; d; d >>= 1)
            g = umn(g, (unsigned)__shfl_xor((int)g, d, 64));
        bool pop = (kk[0] == g);
        #pragma unroll
        for (int u = 0; u < 7; ++u) kk[u] = pop ? kk[u + 1] : kk[u];
        kk[7] = pop ? 0xFFFFFFFFu : kk[7];
        sval = (lane == s) ? g : sval;
    }
    if (lane < NCAND)
        cand[(size_t)row * NCAND + lane] = (int)(sval & 0xFFFFu);
}

// Phase 2 (UNCHANGED, passing since R4): bit-replicate the numpy fp32 pipeline
// on the 16 candidates; top-4 by (q, index); z_q/loss/ste/k_hot.
__global__ void rescore_kernel(const float* __restrict__ ze,
                               const float* __restrict__ cb,
                               const int* __restrict__ cand,
                               float* __restrict__ out_zq,
                               float* __restrict__ out_khot,
                               double* __restrict__ lossAcc) {
    __shared__ float zsh[4][DIM];
    const int wv = threadIdx.x >> 6;
    const int lane = threadIdx.x & 63;
    const int row = blockIdx.x * 4 + wv;

    {
        const float* zp = ze + (size_t)row * DIM + lane * 8;
        float4 v0 = *(const float4*)zp;
        float4 v1 = *(const float4*)(zp + 4);
        *(float4*)&zsh[wv][lane * 8]     = v0;
        *(float4*)&zsh[wv][lane * 8 + 4] = v1;
    }
    __syncthreads();

    // znorm, numpy-pairwise
    float racc = 0.0f;
    {
        const int b = (lane >> 3) & 3;
        const int j = lane & 7;
        const float* zr = &zsh[wv][128 * b + j];
        #pragma unroll
        for (int i = 0; i < 16; ++i) {
            float zk = zr[8 * i];
            float sq = zk * zk;
            asm volatile("" : "+v"(sq));   // block FMA contraction into the add
            racc = racc + sq;
        }
    }
    float t1 = racc + __shfl_xor(racc, 1, 64);
    float t2 = t1 + __shfl_xor(t1, 2, 64);
    float t3 = t2 + __shfl_xor(t2, 4, 64);
    float zn = (__shfl(t3, 0, 64) + __shfl(t3, 8, 64))
             + (__shfl(t3, 16, 64) + __shfl(t3, 24, 64));

    // candidate chains: KC=384 split, sequential FMA, single accumulator each
    float qv = 3.0e38f;
    int   idxv = 0x7fffffff;
    if (lane < NCAND) {
        idxv = cand[(size_t)row * NCAND + lane];
        const float* wp = cb + (size_t)idxv * DIM;
        const float* zz = zsh[wv];
        float acc1 = 0.0f;
        for (int k = 0; k < 384; k += 8) {
            float4 wa = *(const float4*)(wp + k);
            float4 wb = *(const float4*)(wp + k + 4);
            acc1 = __builtin_fmaf(zz[k + 0], wa.x, acc1);
            acc1 = __builtin_fmaf(zz[k + 1], wa.y, acc1);
            acc1 = __builtin_fmaf(zz[k + 2], wa.z, acc1);
            acc1 = __builtin_fmaf(zz[k + 3], wa.w, acc1);
            acc1 = __builtin_fmaf(zz[k + 4], wb.x, acc1);
            acc1 = __builtin_fmaf(zz[k + 5], wb.y, acc1);
            acc1 = __builtin_fmaf(zz[k + 6], wb.z, acc1);
            acc1 = __builtin_fmaf(zz[k + 7], wb.w, acc1);
        }
        float acc2 = 0.0f;
        for (int k = 384; k < 512; k += 8) {
            float4 wa = *(const float4*)(wp + k);
            float4 wb = *(const float4*)(wp + k + 4);
            acc2 = __builtin_fmaf(zz[k + 0], wa.x, acc2);
            acc2 = __builtin_fmaf(zz[k + 1], wa.y, acc2);
            acc2 = __builtin_fmaf(zz[k + 2], wa.z, acc2);
            acc2 = __builtin_fmaf(zz[k + 3], wa.w, acc2);
            acc2 = __builtin_fmaf(zz[k + 4], wb.x, acc2);
            acc2 = __builtin_fmaf(zz[k + 5], wb.y, acc2);
            acc2 = __builtin_fmaf(zz[k + 6], wb.z, acc2);
            acc2 = __builtin_fmaf(zz[k + 7], wb.w, acc2);
        }
        float Cv = acc1 + acc2;
        qv = zn - 2.0f * Cv;
    }

    float q[NCAND]; int id[NCAND];
    #pragma unroll
    for (int c = 0; c < NCAND; ++c) {
        q[c]  = __shfl(qv, c, 64);
        id[c] = __shfl(idxv, c, 64);
    }
    int selIdx[4];
    bool used[NCAND];
    #pragma unroll
    for (int c = 0; c < NCAND; ++c) used[c] = false;
    #pragma unroll
    for (int s = 0; s < 4; ++s) {
        float bq = 3.0e38f; int bi = 0x7fffffff; int bc = -1;
        #pragma unroll
        for (int c = 0; c < NCAND; ++c) {
            bool better = !used[c] && (q[c] < bq || (q[c] == bq && id[c] < bi));
            if (better) { bq = q[c]; bi = id[c]; bc = c; }
        }
        selIdx[s] = bi;
        #pragma unroll
        for (int c = 0; c < NCAND; ++c) used[c] = used[c] || (c == bc);
    }

    float zq[8] = { 0, 0, 0, 0, 0, 0, 0, 0 };
    #pragma unroll
    for (int s = 0; s < 4; ++s) {
        const float* wp = cb + (size_t)selIdx[s] * DIM + lane * 8;
        float4 w0 = *(const float4*)wp;
        float4 w1 = *(const float4*)(wp + 4);
        zq[0] += w0.x; zq[1] += w0.y; zq[2] += w0.z; zq[3] += w0.w;
        zq[4] += w1.x; zq[5] += w1.y; zq[6] += w1.z; zq[7] += w1.w;
    }

    float zf[8];
    {
        const float* zz = &zsh[wv][lane * 8];
        #pragma unroll
        for (int i = 0; i < 8; ++i) zf[i] = zz[i];
    }
    float o[8];
    double l = 0.0;
    #pragma unroll
    for (int i = 0; i < 8; ++i) {
        float zqf  = zq[i] * 0.25f;
        float diff = zqf - zf[i];
        o[i] = zf[i] + diff;
        double ld = (double)diff;
        l += ld * ld;
    }
    {
        float* op = out_zq + (size_t)row * DIM + lane * 8;
        float4 v0 = { o[0], o[1], o[2], o[3] };
        float4 v1 = { o[4], o[5], o[6], o[7] };
        *(float4*)op = v0;
        *(float4*)(op + 4) = v1;
    }
    #pragma unroll
    for (int mm = 32; mm; mm >>= 1) l += __shfl_xor(l, mm, 64);
    if (lane == 0) atomicAdd(lossAcc, l);

    if (lane < 4)
        out_khot[(size_t)row * N_EMB + selIdx[lane]] = 1.0f;
}

__global__ void finalize_kernel(const double* __restrict__ lossAcc,
                                float* __restrict__ out_loss) {
    if (threadIdx.x == 0 && blockIdx.x == 0)
        out_loss[0] = (float)(lossAcc[0] * (1.25 / ((double)N_ROWS * (double)DIM)));
}

extern "C" void kernel_launch(void* const* d_in, const int* in_sizes, int n_in,
                              void* d_out, int out_size, void* d_ws, size_t ws_size,
                              hipStream_t stream) {
    (void)in_sizes; (void)n_in; (void)out_size; (void)ws_size;
    const float* ze = (const float*)d_in[0];
    const float* cb = (const float*)d_in[1];

    float* out      = (float*)d_out;
    float* out_zq   = out;                                   // [16384, 512]
    float* out_loss = out + (size_t)N_ROWS * DIM;            // [1]
    float* out_khot = out_loss + 1;                          // [16384, 8192]

    double* lossAcc = (double*)d_ws;
    int*    cand    = (int*)((char*)d_ws + 16);

    // scratch inside k_hot region, 16B-aligned, consumed before memset
    char* base = (char*)d_out;
    unsigned*       blkTop = (unsigned*)(base + 33554448);               // khot + 12 B
    unsigned short* ze16   = (unsigned short*)(base + 33554448 + 33554432); // + 32 MB
    unsigned short* cb16   = ze16 + (size_t)N_ROWS * DIM;

    hipMemsetAsync(lossAcc, 0, 16, stream);

    convert_bf16_kernel<<<6144, 256, 0, stream>>>(ze, cb, ze16, cb16);
    score_gemm_topk_kernel<<<dim3(N_EMB / 128, N_ROWS / 128), 256, 0, stream>>>(ze16, cb16, blkTop);
    merge_topk_kernel<<<N_ROWS / 4, 256, 0, stream>>>(blkTop, cand);
    hipMemsetAsync(out_khot, 0, (size_t)N_ROWS * N_EMB * sizeof(float), stream);
    rescore_kernel<<<N_ROWS / 4, 256, 0, stream>>>(ze, cb, cand, out_zq, out_khot, lossAcc);
    finalize_kernel<<<1, 64, 0, stream>>>(lossAcc, out_loss);
}

// Round 9
// 1016.840 us; speedup vs baseline: 6.4637x; 1.0955x over previous
//
#include <hip/hip_runtime.h>

#define N_ROWS 16384
#define N_EMB  8192
#define DIM    512
#define NCAND  16

#define GAS __attribute__((address_space(1)))
#define LAS __attribute__((address_space(3)))

// ---------------------------------------------------------------------------
// ws layout:
//   [0]    double lossAcc (16 B, zeroed)
//   [16]   int cand[N_ROWS * NCAND]   (1 MB)
// k_hot region (512 MB at d_out + 33554436 B) is scratch BEFORE rescore:
//   +12 B          : blkTop u32[N_ROWS*64*8]   (32 MB) per-block top-8 keys
//   +12+32 MB      : ze_bf16 u16[N_ROWS*DIM]   (16.8 MB)
//   then           : cb_bf16 u16[N_EMB*DIM]    ( 8.4 MB)
// Consumed by gemm/merge (stream-ordered before rescore overwrites k_hot).
// ---------------------------------------------------------------------------

typedef short  bhalf8  __attribute__((ext_vector_type(8)));
typedef float  floatx4 __attribute__((ext_vector_type(4)));

__device__ __forceinline__ unsigned short f2b(float f) {
    unsigned u = __builtin_bit_cast(unsigned, f);
    unsigned r = (u + 0x7fffu + ((u >> 16) & 1u)) >> 16;   // RNE
    return (unsigned short)r;
}
__device__ __forceinline__ unsigned pk2(float a, float b) {
    return (unsigned)f2b(a) | ((unsigned)f2b(b) << 16);
}
// sortable key: ascending u32 == ascending (score, col); lower col wins ties
__device__ __forceinline__ unsigned mkkey(float s, int col) {
    unsigned short b = f2b(s);
    unsigned short ts = (unsigned short)(b ^ ((b & 0x8000u) ? 0xFFFFu : 0x8000u));
    return ((unsigned)ts << 16) | (unsigned)col;
}
__device__ __forceinline__ unsigned umn(unsigned a, unsigned b) { return a < b ? a : b; }

// fp32 -> bf16 one-time conversion of both inputs (8 elements/thread).
__global__ void convert_bf16_kernel(const float* __restrict__ ze,
                                    const float* __restrict__ cb,
                                    unsigned short* __restrict__ ze16,
                                    unsigned short* __restrict__ cb16) {
    size_t id = (size_t)blockIdx.x * 256 + threadIdx.x;
    const size_t nze = (size_t)N_ROWS * DIM / 8;
    const float* src;
    unsigned short* dst;
    size_t off;
    if (id < nze) { src = ze; dst = ze16; off = id * 8; }
    else          { src = cb; dst = cb16; off = (id - nze) * 8; }
    float4 a = *(const float4*)(src + off);
    float4 b = *(const float4*)(src + off + 4);
    uint4 u = { pk2(a.x, a.y), pk2(a.z, a.w), pk2(b.x, b.y), pk2(b.z, b.w) };
    *(uint4*)(dst + off) = u;
}

// Phase 1a: bf16 MFMA GEMM fused with per-block per-row top-8.
// 128x128 tile, BK=64 (8 K-iters -> half the barrier/vmcnt drains of R8).
// Staging via global_load_lds width=16, unpadded row-major [128][64] bf16
// (128 B rows = 8 chunks); XOR swizzle c_phys = c_log ^ (r&7). All fragment
// rows satisfy r&7 == m&7, so frag reads spread evenly over all 8 bank-quads.
__launch_bounds__(256, 3)
__global__ void score_gemm_topk_kernel(const unsigned short* __restrict__ ze16,
                                       const unsigned short* __restrict__ cb16,
                                       unsigned* __restrict__ blkTop) {
    __shared__ unsigned short Amm[128 * 64];   // 16 KB
    __shared__ unsigned short Bmm[128 * 64];   // 16 KB

    const int t    = threadIdx.x;
    const int lane = t & 63;
    const int w    = t >> 6;
    const int rowBase = blockIdx.y * 128;
    const int colBase = blockIdx.x * 128;
    const int cblk    = blockIdx.x;

    const int m = lane & 15;
    const int q = lane >> 4;

    floatx4 acc[2][8];
    #pragma unroll
    for (int i = 0; i < 2; ++i)
        #pragma unroll
        for (int j = 0; j < 8; ++j)
            acc[i][j] = (floatx4){0.0f, 0.0f, 0.0f, 0.0f};

    // staging: call k covers tile rows k*32 + (t>>3); phys chunk t&7 holds
    // global chunk (t&7) ^ ((t>>3)&7)
    const int tr = t >> 3;
    const int cg = (t & 7) ^ (tr & 7);
    const unsigned short* pa = ze16 + (size_t)(rowBase + tr) * DIM + cg * 8;
    const unsigned short* pb = cb16 + (size_t)(colBase + tr) * DIM + cg * 8;

    // frag chunk offsets (elements): logical chunk h*4+q, row-swizzle m&7
    const int ch0 = ((0 * 4 + q) ^ (m & 7)) * 8;
    const int ch1 = ((1 * 4 + q) ^ (m & 7)) * 8;

    for (int k0 = 0; k0 < DIM; k0 += 64) {
        __syncthreads();
        #pragma unroll
        for (int k = 0; k < 4; ++k)
            __builtin_amdgcn_global_load_lds((const GAS void*)(pa + (size_t)k * 32 * DIM + k0),
                                             (LAS void*)(Amm + (k * 256 + w * 64) * 8), 16, 0, 0);
        #pragma unroll
        for (int k = 0; k < 4; ++k)
            __builtin_amdgcn_global_load_lds((const GAS void*)(pb + (size_t)k * 32 * DIM + k0),
                                             (LAS void*)(Bmm + (k * 256 + w * 64) * 8), 16, 0, 0);
        __syncthreads();

        #pragma unroll
        for (int h = 0; h < 2; ++h) {
            const int ch = h ? ch1 : ch0;
            bhalf8 af0 = *(bhalf8*)&Amm[(w * 32 + m) * 64 + ch];
            bhalf8 af1 = *(bhalf8*)&Amm[(w * 32 + 16 + m) * 64 + ch];
            #pragma unroll
            for (int j = 0; j < 8; ++j) {
                bhalf8 bf = *(bhalf8*)&Bmm[(j * 16 + m) * 64 + ch];
                acc[0][j] = __builtin_amdgcn_mfma_f32_16x16x32_bf16(af0, bf, acc[0][j], 0, 0, 0);
                acc[1][j] = __builtin_amdgcn_mfma_f32_16x16x32_bf16(af1, bf, acc[1][j], 0, 0, 0);
            }
        }
    }

    // Epilogue (proven R7/R8). C/D layout: col = lane&15, row = quad*4 + reg.
    #pragma unroll
    for (int i = 0; i < 2; ++i) {
        #pragma unroll
        for (int reg = 0; reg < 4; ++reg) {
            const int grow = rowBase + w * 32 + i * 16 + q * 4 + reg;
            unsigned kk[8];
            #pragma unroll
            for (int j = 0; j < 8; ++j) {
                unsigned e = mkkey(-acc[i][j][reg], colBase + j * 16 + m);
                kk[j] = e;
                #pragma unroll
                for (int s = 7; s > 0; --s) {
                    if (s <= j) {
                        unsigned lo = umn(kk[s - 1], kk[s]);
                        unsigned hi = kk[s - 1] < kk[s] ? kk[s] : kk[s - 1];
                        kk[s - 1] = lo; kk[s] = hi;
                    }
                }
            }
            unsigned sval = 0;
            #pragma unroll
            for (int s = 0; s < 8; ++s) {
                unsigned g = kk[0];
                g = umn(g, (unsigned)__shfl_xor((int)g, 1, 64));
                g = umn(g, (unsigned)__shfl_xor((int)g, 2, 64));
                g = umn(g, (unsigned)__shfl_xor((int)g, 4, 64));
                g = umn(g, (unsigned)__shfl_xor((int)g, 8, 64));
                bool pop = (kk[0] == g);
                #pragma unroll
                for (int u = 0; u < 7; ++u) kk[u] = pop ? kk[u + 1] : kk[u];
                kk[7] = pop ? 0xFFFFFFFFu : kk[7];
                sval = (m == s) ? g : sval;
            }
            if (m < 8)
                blkTop[((size_t)grow * 64 + cblk) * 8 + m] = sval;
        }
    }
}

// Phase 1b: merge 64 blocks x 8 keys per row -> top-16 candidates.
__global__ void merge_topk_kernel(const unsigned* __restrict__ blkTop,
                                  int* __restrict__ cand) {
    const int wv   = threadIdx.x >> 6;
    const int lane = threadIdx.x & 63;
    const int row  = blockIdx.x * 4 + wv;
    const uint4* base = (const uint4*)(blkTop + (size_t)row * 512);

    uint4 a = base[lane * 2];
    uint4 b = base[lane * 2 + 1];
    unsigned in[8] = { a.x, a.y, a.z, a.w, b.x, b.y, b.z, b.w };
    unsigned kk[8];
    #pragma unroll
    for (int j = 0; j < 8; ++j) {
        kk[j] = in[j];
        #pragma unroll
        for (int s = 7; s > 0; --s) {
            if (s <= j) {
                unsigned lo = umn(kk[s - 1], kk[s]);
                unsigned hi = kk[s - 1] < kk[s] ? kk[s] : kk[s - 1];
                kk[s - 1] = lo; kk[s] = hi;
            }
        }
    }

    unsigned sval = 0;
    #pragma unroll
    for (int s = 0; s < NCAND; ++s) {
        unsigned g = kk[0];
        #pragma unroll
        for (int d = 32; d; d >>= 1)
            g = umn(g, (unsigned)__shfl_xor((int)g, d, 64));
        bool pop = (kk[0] == g);
        #pragma unroll
        for (int u = 0; u < 7; ++u) kk[u] = pop ? kk[u + 1] : kk[u];
        kk[7] = pop ? 0xFFFFFFFFu : kk[7];
        sval = (lane == s) ? g : sval;
    }
    if (lane < NCAND)
        cand[(size_t)row * NCAND + lane] = (int)(sval & 0xFFFFu);
}

// Phase 2: exact numpy-fp32 replica rescore (selection logic unchanged since
// R4) + FULL k_hot row write (zeros + the 4 ones in one pass; replaces the
// 512 MB memset).
__global__ void rescore_kernel(const float* __restrict__ ze,
                               const float* __restrict__ cb,
                               const int* __restrict__ cand,
                               float* __restrict__ out_zq,
                               float* __restrict__ out_khot,
                               double* __restrict__ lossAcc) {
    __shared__ float zsh[4][DIM];
    const int wv = threadIdx.x >> 6;
    const int lane = threadIdx.x & 63;
    const int row = blockIdx.x * 4 + wv;

    {
        const float* zp = ze + (size_t)row * DIM + lane * 8;
        float4 v0 = *(const float4*)zp;
        float4 v1 = *(const float4*)(zp + 4);
        *(float4*)&zsh[wv][lane * 8]     = v0;
        *(float4*)&zsh[wv][lane * 8 + 4] = v1;
    }
    __syncthreads();

    // znorm, numpy-pairwise
    float racc = 0.0f;
    {
        const int b = (lane >> 3) & 3;
        const int j = lane & 7;
        const float* zr = &zsh[wv][128 * b + j];
        #pragma unroll
        for (int i = 0; i < 16; ++i) {
            float zk = zr[8 * i];
            float sq = zk * zk;
            asm volatile("" : "+v"(sq));   // block FMA contraction into the add
            racc = racc + sq;
        }
    }
    float t1 = racc + __shfl_xor(racc, 1, 64);
    float t2 = t1 + __shfl_xor(t1, 2, 64);
    float t3 = t2 + __shfl_xor(t2, 4, 64);
    float zn = (__shfl(t3, 0, 64) + __shfl(t3, 8, 64))
             + (__shfl(t3, 16, 64) + __shfl(t3, 24, 64));

    // candidate chains: KC=384 split, sequential FMA, single accumulator each
    float qv = 3.0e38f;
    int   idxv = 0x7fffffff;
    if (lane < NCAND) {
        idxv = cand[(size_t)row * NCAND + lane];
        const float* wp = cb + (size_t)idxv * DIM;
        const float* zz = zsh[wv];
        float acc1 = 0.0f;
        for (int k = 0; k < 384; k += 8) {
            float4 wa = *(const float4*)(wp + k);
            float4 wb = *(const float4*)(wp + k + 4);
            acc1 = __builtin_fmaf(zz[k + 0], wa.x, acc1);
            acc1 = __builtin_fmaf(zz[k + 1], wa.y, acc1);
            acc1 = __builtin_fmaf(zz[k + 2], wa.z, acc1);
            acc1 = __builtin_fmaf(zz[k + 3], wa.w, acc1);
            acc1 = __builtin_fmaf(zz[k + 4], wb.x, acc1);
            acc1 = __builtin_fmaf(zz[k + 5], wb.y, acc1);
            acc1 = __builtin_fmaf(zz[k + 6], wb.z, acc1);
            acc1 = __builtin_fmaf(zz[k + 7], wb.w, acc1);
        }
        float acc2 = 0.0f;
        for (int k = 384; k < 512; k += 8) {
            float4 wa = *(const float4*)(wp + k);
            float4 wb = *(const float4*)(wp + k + 4);
            acc2 = __builtin_fmaf(zz[k + 0], wa.x, acc2);
            acc2 = __builtin_fmaf(zz[k + 1], wa.y, acc2);
            acc2 = __builtin_fmaf(zz[k + 2], wa.z, acc2);
            acc2 = __builtin_fmaf(zz[k + 3], wa.w, acc2);
            acc2 = __builtin_fmaf(zz[k + 4], wb.x, acc2);
            acc2 = __builtin_fmaf(zz[k + 5], wb.y, acc2);
            acc2 = __builtin_fmaf(zz[k + 6], wb.z, acc2);
            acc2 = __builtin_fmaf(zz[k + 7], wb.w, acc2);
        }
        float Cv = acc1 + acc2;
        qv = zn - 2.0f * Cv;
    }

    float q[NCAND]; int id[NCAND];
    #pragma unroll
    for (int c = 0; c < NCAND; ++c) {
        q[c]  = __shfl(qv, c, 64);
        id[c] = __shfl(idxv, c, 64);
    }
    int selIdx[4];
    bool used[NCAND];
    #pragma unroll
    for (int c = 0; c < NCAND; ++c) used[c] = false;
    #pragma unroll
    for (int s = 0; s < 4; ++s) {
        float bq = 3.0e38f; int bi = 0x7fffffff; int bc = -1;
        #pragma unroll
        for (int c = 0; c < NCAND; ++c) {
            bool better = !used[c] && (q[c] < bq || (q[c] == bq && id[c] < bi));
            if (better) { bq = q[c]; bi = id[c]; bc = c; }
        }
        selIdx[s] = bi;
        #pragma unroll
        for (int c = 0; c < NCAND; ++c) used[c] = used[c] || (c == bc);
    }

    float zq[8] = { 0, 0, 0, 0, 0, 0, 0, 0 };
    #pragma unroll
    for (int s = 0; s < 4; ++s) {
        const float* wp = cb + (size_t)selIdx[s] * DIM + lane * 8;
        float4 w0 = *(const float4*)wp;
        float4 w1 = *(const float4*)(wp + 4);
        zq[0] += w0.x; zq[1] += w0.y; zq[2] += w0.z; zq[3] += w0.w;
        zq[4] += w1.x; zq[5] += w1.y; zq[6] += w1.z; zq[7] += w1.w;
    }

    float zf[8];
    {
        const float* zz = &zsh[wv][lane * 8];
        #pragma unroll
        for (int i = 0; i < 8; ++i) zf[i] = zz[i];
    }
    float o[8];
    double l = 0.0;
    #pragma unroll
    for (int i = 0; i < 8; ++i) {
        float zqf  = zq[i] * 0.25f;
        float diff = zqf - zf[i];
        o[i] = zf[i] + diff;
        double ld = (double)diff;
        l += ld * ld;
    }
    {
        float* op = out_zq + (size_t)row * DIM + lane * 8;
        float4 v0 = { o[0], o[1], o[2], o[3] };
        float4 v1 = { o[4], o[5], o[6], o[7] };
        *(float4*)op = v0;
        *(float4*)(op + 4) = v1;
    }
    #pragma unroll
    for (int mm = 32; mm; mm >>= 1) l += __shfl_xor(l, mm, 64);
    if (lane == 0) atomicAdd(lossAcc, l);

    // full k_hot row write: lane owns cols {j*256 + lane*4 + e}.
    // hot mask: col -> j = col>>8, e = col&3, owner lane = (col>>2)&63.
    unsigned hotm[4] = { 0u, 0u, 0u, 0u };
    #pragma unroll
    for (int s = 0; s < 4; ++s) {
        int si = selIdx[s];
        bool own = ((si >> 2) & 63) == lane;
        int jj = si >> 8;
        unsigned bit = 1u << (((jj & 7) << 2) | (si & 3));
        int word = jj >> 3;
        #pragma unroll
        for (int wd = 0; wd < 4; ++wd)
            hotm[wd] |= (own && word == wd) ? bit : 0u;
    }
    float* kp = out_khot + (size_t)row * N_EMB;
    #pragma unroll
    for (int j = 0; j < 32; ++j) {
        unsigned bits = (hotm[j >> 3] >> ((j & 7) * 4)) & 0xFu;
        float4 v;
        v.x = (bits & 1u) ? 1.0f : 0.0f;
        v.y = (bits & 2u) ? 1.0f : 0.0f;
        v.z = (bits & 4u) ? 1.0f : 0.0f;
        v.w = (bits & 8u) ? 1.0f : 0.0f;
        *(float4*)(kp + j * 256 + lane * 4) = v;
    }
}

__global__ void finalize_kernel(const double* __restrict__ lossAcc,
                                float* __restrict__ out_loss) {
    if (threadIdx.x == 0 && blockIdx.x == 0)
        out_loss[0] = (float)(lossAcc[0] * (1.25 / ((double)N_ROWS * (double)DIM)));
}

extern "C" void kernel_launch(void* const* d_in, const int* in_sizes, int n_in,
                              void* d_out, int out_size, void* d_ws, size_t ws_size,
                              hipStream_t stream) {
    (void)in_sizes; (void)n_in; (void)out_size; (void)ws_size;
    const float* ze = (const float*)d_in[0];
    const float* cb = (const float*)d_in[1];

    float* out      = (float*)d_out;
    float* out_zq   = out;                                   // [16384, 512]
    float* out_loss = out + (size_t)N_ROWS * DIM;            // [1]
    float* out_khot = out_loss + 1;                          // [16384, 8192]

    double* lossAcc = (double*)d_ws;
    int*    cand    = (int*)((char*)d_ws + 16);

    // scratch inside k_hot region, 16B-aligned, consumed before rescore
    char* base = (char*)d_out;
    unsigned*       blkTop = (unsigned*)(base + 33554448);                  // khot + 12 B
    unsigned short* ze16   = (unsigned short*)(base + 33554448 + 33554432); // + 32 MB
    unsigned short* cb16   = ze16 + (size_t)N_ROWS * DIM;

    hipMemsetAsync(lossAcc, 0, 16, stream);

    convert_bf16_kernel<<<6144, 256, 0, stream>>>(ze, cb, ze16, cb16);
    score_gemm_topk_kernel<<<dim3(N_EMB / 128, N_ROWS / 128), 256, 0, stream>>>(ze16, cb16, blkTop);
    merge_topk_kernel<<<N_ROWS / 4, 256, 0, stream>>>(blkTop, cand);
    rescore_kernel<<<N_ROWS / 4, 256, 0, stream>>>(ze, cb, cand, out_zq, out_khot, lossAcc);
    finalize_kernel<<<1, 64, 0, stream>>>(lossAcc, out_loss);
}